// Round 4
// baseline (628.355 us; speedup 1.0000x reference)
//
#include <hip/hip_runtime.h>
#include <hip/hip_bf16.h>
#include <math.h>

typedef __attribute__((ext_vector_type(8))) short short8;
typedef __attribute__((ext_vector_type(4))) float f32x4;

__device__ __forceinline__ float sigm(float v) { return 1.0f / (1.0f + expf(-v)); }
__device__ __forceinline__ unsigned short f2b(float f) {
  __hip_bfloat16 h = __float2bfloat16(f);
  return __builtin_bit_cast(unsigned short, h);
}

// ---------------------------------------------------------------------------
// K0: pre-convert eW1[:, :2048] -> Wb1 bf16 [128][2048], dW4 -> Wb4 bf16 [2048][128]
// ---------------------------------------------------------------------------
__global__ __launch_bounds__(256) void wcvt_kernel(
    const float* __restrict__ eW1, const float* __restrict__ dW4,
    unsigned short* __restrict__ Wb1, unsigned short* __restrict__ Wb4)
{
  int idx = blockIdx.x * 256 + threadIdx.x;   // 0..262143
  int o = idx >> 11, k = idx & 2047;
  Wb1[idx] = f2b(eW1[(size_t)o * 2049 + k]);
  Wb4[idx] = f2b(dW4[idx]);
}

// ---------------------------------------------------------------------------
// K1: MFMA dual GEMM: accx = x@W.T, accd = xd@W.T (bf16, fp32 acc)
// v4: in-block split-K TLP experiment. 512 thr / 8 waves; wave-group g=w>>2
// computes K-half g with the simple round-2 loop (low VGPR); halves combined
// through LDS; epilogue by group 0. 4 blocks/CU -> 32 waves/CU resident.
// ---------------------------------------------------------------------------
__global__ __launch_bounds__(512, 8) void enc1_mfma(
    const float* __restrict__ x, const float* __restrict__ xd,
    const float* __restrict__ tr, const unsigned short* __restrict__ Wb,
    const float* __restrict__ Wfull, const float* __restrict__ bias,
    float* __restrict__ a1, float* __restrict__ dz1)
{
  __shared__ float combx[16 * 128];
  __shared__ float combd[16 * 128];
  const int t = threadIdx.x;
  const int w = t >> 6, L = t & 63, q = L >> 4, ln = L & 15;
  const int wc = w & 3;        // column group 0..3
  const int g  = w >> 2;       // K-half 0..1
  const int r0 = blockIdx.x * 16;
  const float* xA = x  + (size_t)(r0 + ln) * 2048;
  const float* dA = xd + (size_t)(r0 + ln) * 2048;
  const unsigned short* wB0 = Wb + (size_t)(wc * 32 + ln) * 2048;
  const unsigned short* wB1 = Wb + (size_t)(wc * 32 + 16 + ln) * 2048;

  f32x4 accx0 = (f32x4){0.f, 0.f, 0.f, 0.f};
  f32x4 accx1 = accx0, accd0 = accx0, accd1 = accx0;

  const int ktEnd = g * 32 + 32;
#pragma unroll 2
  for (int kt = g * 32; kt < ktEnd; ++kt) {
    const int kb = kt * 32 + q * 8;
    float4 xv0 = *(const float4*)(xA + kb);
    float4 xv1 = *(const float4*)(xA + kb + 4);
    float4 dv0 = *(const float4*)(dA + kb);
    float4 dv1 = *(const float4*)(dA + kb + 4);
    short8 bw0 = *(const short8*)(wB0 + kb);
    short8 bw1 = *(const short8*)(wB1 + kb);
    short8 ax, ad;
    ax[0] = (short)f2b(xv0.x); ax[1] = (short)f2b(xv0.y);
    ax[2] = (short)f2b(xv0.z); ax[3] = (short)f2b(xv0.w);
    ax[4] = (short)f2b(xv1.x); ax[5] = (short)f2b(xv1.y);
    ax[6] = (short)f2b(xv1.z); ax[7] = (short)f2b(xv1.w);
    ad[0] = (short)f2b(dv0.x); ad[1] = (short)f2b(dv0.y);
    ad[2] = (short)f2b(dv0.z); ad[3] = (short)f2b(dv0.w);
    ad[4] = (short)f2b(dv1.x); ad[5] = (short)f2b(dv1.y);
    ad[6] = (short)f2b(dv1.z); ad[7] = (short)f2b(dv1.w);
    accx0 = __builtin_amdgcn_mfma_f32_16x16x32_bf16(ax, bw0, accx0, 0, 0, 0);
    accx1 = __builtin_amdgcn_mfma_f32_16x16x32_bf16(ax, bw1, accx1, 0, 0, 0);
    accd0 = __builtin_amdgcn_mfma_f32_16x16x32_bf16(ad, bw0, accd0, 0, 0, 0);
    accd1 = __builtin_amdgcn_mfma_f32_16x16x32_bf16(ad, bw1, accd1, 0, 0, 0);
  }

  // K-half 1 deposits its partials in LDS
  if (g == 1) {
#pragma unroll
    for (int r = 0; r < 4; ++r) {
      const int row = q * 4 + r;
      combx[row * 128 + wc * 32 + ln]      = accx0[r];
      combx[row * 128 + wc * 32 + 16 + ln] = accx1[r];
      combd[row * 128 + wc * 32 + ln]      = accd0[r];
      combd[row * 128 + wc * 32 + 16 + ln] = accd1[r];
    }
  }
  __syncthreads();
  // K-half 0 combines + epilogue: C[row = q*4 + r][col = wc*32 + n*16 + ln]
  if (g == 0) {
#pragma unroll
    for (int r = 0; r < 4; ++r) {
      const int lrow = q * 4 + r;
      const int row = r0 + lrow;
      const float trv = tr[row];
      {
        const int col = wc * 32 + ln;
        const float wl = Wfull[(size_t)col * 2049 + 2048];
        float p  = accx0[r] + combx[lrow * 128 + col] + trv * wl + bias[col];
        float gg = accd0[r] + combd[lrow * 128 + col] + trv * wl;
        float a = sigm(p);
        a1 [(size_t)row * 128 + col] = a;
        dz1[(size_t)row * 128 + col] = a * (1.f - a) * gg;
      }
      {
        const int col = wc * 32 + 16 + ln;
        const float wl = Wfull[(size_t)col * 2049 + 2048];
        float p  = accx1[r] + combx[lrow * 128 + col] + trv * wl + bias[col];
        float gg = accd1[r] + combd[lrow * 128 + col] + trv * wl;
        float a = sigm(p);
        a1 [(size_t)row * 128 + col] = a;
        dz1[(size_t)row * 128 + col] = a * (1.f - a) * gg;
      }
    }
  }
}

// ---------------------------------------------------------------------------
// K2: encoder layers 2-4. 16 rows/block, k-outer multi-accumulator loops.
// ---------------------------------------------------------------------------
__global__ __launch_bounds__(256) void enc_small_kernel(
    const float* __restrict__ a1, const float* __restrict__ dz1,
    const float* __restrict__ W2, const float* __restrict__ b2,
    const float* __restrict__ W3, const float* __restrict__ b3,
    const float* __restrict__ W4, const float* __restrict__ b4,
    const float* __restrict__ coef, const float* __restrict__ size_in,
    const float* __restrict__ treat,
    float* __restrict__ z_out, float* __restrict__ zdp_out,
    float* __restrict__ pe0, float* __restrict__ pe1, float* __restrict__ pe2)
{
  __shared__ float sW2[64 * 129];
  __shared__ float sW3[32 * 65];
  __shared__ float sW4[96];
  __shared__ float sB2[64], sB3[32], sB4[3], sC[21];
  __shared__ __align__(16) float a1s[16 * 128], d1s[16 * 128];
  __shared__ float a2s[16 * 64],  d2s[16 * 64];
  __shared__ float a3s[16 * 32],  d3s[16 * 32];
  __shared__ float zs[48], zds[48];
  __shared__ float rowl[16][3];
  const int t = threadIdx.x;
  for (int i = t; i < 64 * 128; i += 256) sW2[(i >> 7) * 129 + (i & 127)] = W2[i];
  for (int i = t; i < 32 * 64;  i += 256) sW3[(i >> 6) * 65  + (i & 63)]  = W3[i];
  if (t < 96) sW4[t] = W4[t];
  if (t < 64) sB2[t] = b2[t];
  if (t < 32) sB3[t] = b3[t];
  if (t < 3)  sB4[t] = b4[t];
  if (t < 21) sC[t]  = coef[t];
  const int r0 = blockIdx.x * 16;
  {
    const float4* a1g = (const float4*)(a1  + (size_t)r0 * 128);
    const float4* d1g = (const float4*)(dz1 + (size_t)r0 * 128);
    float4* a1s4 = (float4*)a1s;
    float4* d1s4 = (float4*)d1s;
#pragma unroll
    for (int i = 0; i < 2; ++i) {
      a1s4[t + i * 256] = a1g[t + i * 256];
      d1s4[t + i * 256] = d1g[t + i * 256];
    }
  }
  __syncthreads();
  // layer 2: 16 rows x 64 outs; thread t -> o = t&63, rows rb, rb+4, rb+8, rb+12
  {
    const int o = t & 63, rb = t >> 6;
    float p[4] = {0.f, 0.f, 0.f, 0.f}, g[4] = {0.f, 0.f, 0.f, 0.f};
#pragma unroll 4
    for (int k = 0; k < 128; ++k) {
      const float wv = sW2[o * 129 + k];
#pragma unroll
      for (int u = 0; u < 4; ++u) {
        p[u] = fmaf(wv, a1s[(rb + u * 4) * 128 + k], p[u]);
        g[u] = fmaf(wv, d1s[(rb + u * 4) * 128 + k], g[u]);
      }
    }
#pragma unroll
    for (int u = 0; u < 4; ++u) {
      float a = sigm(p[u] + sB2[o]);
      a2s[(rb + u * 4) * 64 + o] = a;
      d2s[(rb + u * 4) * 64 + o] = a * (1.f - a) * g[u];
    }
  }
  __syncthreads();
  // layer 3: 16 rows x 32 outs; thread t -> o = t&31, rows r3, r3+8
  {
    const int o = t & 31, r3 = t >> 5;
    float p[2] = {0.f, 0.f}, g[2] = {0.f, 0.f};
#pragma unroll 4
    for (int k = 0; k < 64; ++k) {
      const float wv = sW3[o * 65 + k];
#pragma unroll
      for (int u = 0; u < 2; ++u) {
        p[u] = fmaf(wv, a2s[(r3 + u * 8) * 64 + k], p[u]);
        g[u] = fmaf(wv, d2s[(r3 + u * 8) * 64 + k], g[u]);
      }
    }
#pragma unroll
    for (int u = 0; u < 2; ++u) {
      float a = sigm(p[u] + sB3[o]);
      a3s[(r3 + u * 8) * 32 + o] = a;
      d3s[(r3 + u * 8) * 32 + o] = a * (1.f - a) * g[u];
    }
  }
  __syncthreads();
  if (t < 48) {
    const int r = t / 3, j = t % 3;
    float p = 0.f, g = 0.f;
#pragma unroll
    for (int k = 0; k < 32; ++k) {
      float wv = sW4[j * 32 + k];
      p = fmaf(wv, a3s[r * 32 + k], p);
      g = fmaf(wv, d3s[r * 32 + k], g);
    }
    float zv = p + sB4[j];
    zs [r * 3 + j] = zv;
    zds[r * 3 + j] = g;
    z_out[(size_t)(r0 + r) * 3 + j] = zv;
  }
  __syncthreads();
  if (t < 16) {
    const int r = t;
    float s = zs[r * 3 + 0], d = zs[r * 3 + 1], tt = zs[r * 3 + 2];
    float th[7] = {1.f, s, s * s, s * d, s * tt, s * s * d, s * s * tt};
    float sz = 0.f;
    for (int j = 0; j < 3; ++j) {
      float zp = 0.f;
#pragma unroll
      for (int i = 0; i < 7; ++i) zp = fmaf(th[i], sC[i * 3 + j], zp);
      zdp_out[(size_t)(r0 + r) * 3 + j] = zp;
      float e = zds[r * 3 + j] - zp;
      sz += e * e;
    }
    float e0 = s - size_in[r0 + r];
    float logit = tt;
    float trv = treat[r0 + r];
    float lt = fmaxf(logit, 0.f) + log1pf(expf(-fabsf(logit))) - logit * trv;
    rowl[r][0] = e0 * e0; rowl[r][1] = lt; rowl[r][2] = sz;
  }
  __syncthreads();
  if (t == 0) {
    float s0 = 0, s1 = 0, s2 = 0;
    for (int r = 0; r < 16; ++r) { s0 += rowl[r][0]; s1 += rowl[r][1]; s2 += rowl[r][2]; }
    pe0[blockIdx.x] = s0;
    pe1[blockIdx.x] = s1;
    pe2[blockIdx.x] = s2;
  }
}

// ---------------------------------------------------------------------------
// K3: decoder layers 1-3. 16 rows/block, k-outer multi-accumulator loops.
// ---------------------------------------------------------------------------
__global__ __launch_bounds__(256) void dec_small_kernel(
    const float* __restrict__ z_in, const float* __restrict__ zdp,
    const float* __restrict__ W1, const float* __restrict__ b1,
    const float* __restrict__ W2, const float* __restrict__ b2,
    const float* __restrict__ W3, const float* __restrict__ b3,
    unsigned short* __restrict__ h3b, unsigned short* __restrict__ g3b)
{
  __shared__ float sW1[96], sB1[32];
  __shared__ float sW2[64 * 33], sB2[64];
  __shared__ float sW3[128 * 65], sB3[128];
  __shared__ float zr[48], zp[48];
  __shared__ float h1s[16 * 32], g1s[16 * 32];
  __shared__ float h2s[16 * 64], g2s[16 * 64];
  const int t = threadIdx.x;
  for (int i = t; i < 64 * 32;  i += 256) sW2[(i >> 5) * 33 + (i & 31)] = W2[i];
  for (int i = t; i < 128 * 64; i += 256) sW3[(i >> 6) * 65 + (i & 63)] = W3[i];
  if (t < 96)  sW1[t] = W1[t];
  if (t < 32)  sB1[t] = b1[t];
  if (t < 64)  sB2[t] = b2[t];
  if (t < 128) sB3[t] = b3[t];
  const int r0 = blockIdx.x * 16;
  if (t < 48) { zr[t] = z_in[(size_t)r0 * 3 + t]; zp[t] = zdp[(size_t)r0 * 3 + t]; }
  __syncthreads();
  // layer 1: 16 rows x 32 outs; thread -> o = t&31, rows r, r+8
  {
    const int o = t & 31, rb = t >> 5;
    float p[2], g[2];
#pragma unroll
    for (int u = 0; u < 2; ++u) {
      const int r = rb + u * 8;
      float pp = sB1[o], gg = 0.f;
#pragma unroll
      for (int k = 0; k < 3; ++k) {
        float wv = sW1[o * 3 + k];
        pp = fmaf(wv, zr[r * 3 + k], pp);
        gg = fmaf(wv, zp[r * 3 + k], gg);
      }
      p[u] = pp; g[u] = gg;
    }
#pragma unroll
    for (int u = 0; u < 2; ++u) {
      const int r = rb + u * 8;
      float h = sigm(p[u]);
      h1s[r * 32 + o] = h; g1s[r * 32 + o] = h * (1.f - h) * g[u];
    }
  }
  __syncthreads();
  // layer 2: 16 rows x 64 outs; thread -> o = t&63, rows rb, rb+4, rb+8, rb+12
  {
    const int o = t & 63, rb = t >> 6;
    float p[4], g[4];
#pragma unroll
    for (int u = 0; u < 4; ++u) { p[u] = sB2[o]; g[u] = 0.f; }
#pragma unroll 4
    for (int k = 0; k < 32; ++k) {
      const float wv = sW2[o * 33 + k];
#pragma unroll
      for (int u = 0; u < 4; ++u) {
        p[u] = fmaf(wv, h1s[(rb + u * 4) * 32 + k], p[u]);
        g[u] = fmaf(wv, g1s[(rb + u * 4) * 32 + k], g[u]);
      }
    }
#pragma unroll
    for (int u = 0; u < 4; ++u) {
      float h = sigm(p[u]);
      h2s[(rb + u * 4) * 64 + o] = h;
      g2s[(rb + u * 4) * 64 + o] = h * (1.f - h) * g[u];
    }
  }
  __syncthreads();
  // layer 3: 16 rows x 128 outs; thread -> o = t&127, rows rb2 + 2u (u<8)
  {
    const int o = t & 127, rb2 = t >> 7;
    float p[8], g[8];
#pragma unroll
    for (int u = 0; u < 8; ++u) { p[u] = sB3[o]; g[u] = 0.f; }
#pragma unroll 4
    for (int k = 0; k < 64; ++k) {
      const float wv = sW3[o * 65 + k];
#pragma unroll
      for (int u = 0; u < 8; ++u) {
        p[u] = fmaf(wv, h2s[(rb2 + u * 2) * 64 + k], p[u]);
        g[u] = fmaf(wv, g2s[(rb2 + u * 2) * 64 + k], g[u]);
      }
    }
#pragma unroll
    for (int u = 0; u < 8; ++u) {
      const int r = rb2 + u * 2;
      float h = sigm(p[u]);
      h3b[(size_t)(r0 + r) * 128 + o] = f2b(h);
      g3b[(size_t)(r0 + r) * 128 + o] = f2b(h * (1.f - h) * g[u]);
    }
  }
}

// ---------------------------------------------------------------------------
// K4: MFMA dual GEMM: xhat = h3@W4.T + b, xdp = g3@W4.T; fused recon/sindy_x.
// Early-issued epilogue loads; float4 epilogue; per-block partial sums.
// ---------------------------------------------------------------------------
__global__ __launch_bounds__(256, 2) void dec4_mfma(
    const unsigned short* __restrict__ h3b, const unsigned short* __restrict__ g3b,
    const unsigned short* __restrict__ Wb, const float* __restrict__ bias,
    const float* __restrict__ x, const float* __restrict__ xd,
    float* __restrict__ xhat, float* __restrict__ pr, float* __restrict__ ps)
{
  __shared__ float sH[32 * 132];
  __shared__ float sG[32 * 132];
  __shared__ float red[8];
  const int t = threadIdx.x, w = t >> 6, L = t & 63, q = L >> 4, ln = L & 15;
  const int r0 = blockIdx.x * 32, c0 = blockIdx.y * 128;

  f32x4 accH[2][2], accG[2][2];
#pragma unroll
  for (int m = 0; m < 2; ++m)
#pragma unroll
    for (int n = 0; n < 2; ++n) {
      accH[m][n] = (f32x4){0.f, 0.f, 0.f, 0.f};
      accG[m][n] = (f32x4){0.f, 0.f, 0.f, 0.f};
    }

  const size_t a0 = (size_t)(r0 + ln) * 128;
  const size_t a1r = (size_t)(r0 + 16 + ln) * 128;
  const size_t b0 = (size_t)(c0 + w * 32 + ln) * 128;
  const size_t b1 = (size_t)(c0 + w * 32 + 16 + ln) * 128;

#pragma unroll
  for (int ks = 0; ks < 4; ++ks) {
    const int kb = ks * 32 + q * 8;
    short8 ah0 = *(const short8*)&h3b[a0 + kb];
    short8 ah1 = *(const short8*)&h3b[a1r + kb];
    short8 ag0 = *(const short8*)&g3b[a0 + kb];
    short8 ag1 = *(const short8*)&g3b[a1r + kb];
    short8 bw0 = *(const short8*)&Wb[b0 + kb];
    short8 bw1 = *(const short8*)&Wb[b1 + kb];
    accH[0][0] = __builtin_amdgcn_mfma_f32_16x16x32_bf16(ah0, bw0, accH[0][0], 0, 0, 0);
    accH[0][1] = __builtin_amdgcn_mfma_f32_16x16x32_bf16(ah0, bw1, accH[0][1], 0, 0, 0);
    accH[1][0] = __builtin_amdgcn_mfma_f32_16x16x32_bf16(ah1, bw0, accH[1][0], 0, 0, 0);
    accH[1][1] = __builtin_amdgcn_mfma_f32_16x16x32_bf16(ah1, bw1, accH[1][1], 0, 0, 0);
    accG[0][0] = __builtin_amdgcn_mfma_f32_16x16x32_bf16(ag0, bw0, accG[0][0], 0, 0, 0);
    accG[0][1] = __builtin_amdgcn_mfma_f32_16x16x32_bf16(ag0, bw1, accG[0][1], 0, 0, 0);
    accG[1][0] = __builtin_amdgcn_mfma_f32_16x16x32_bf16(ag1, bw0, accG[1][0], 0, 0, 0);
    accG[1][1] = __builtin_amdgcn_mfma_f32_16x16x32_bf16(ag1, bw1, accG[1][1], 0, 0, 0);
  }

  // early-issue epilogue loads (independent of MFMA results)
  const int erow = t >> 3;
  const int ecb = (t & 7) * 4;
  const size_t gbase = (size_t)(r0 + erow) * 2048 + c0 + ecb;
  float4 exv0 = *(const float4*)&x [gbase];
  float4 exv1 = *(const float4*)&x [gbase + 32];
  float4 exv2 = *(const float4*)&x [gbase + 64];
  float4 exv3 = *(const float4*)&x [gbase + 96];
  float4 edv0 = *(const float4*)&xd[gbase];
  float4 edv1 = *(const float4*)&xd[gbase + 32];
  float4 edv2 = *(const float4*)&xd[gbase + 64];
  float4 edv3 = *(const float4*)&xd[gbase + 96];
  float4 ebv0 = *(const float4*)&bias[c0 + ecb];
  float4 ebv1 = *(const float4*)&bias[c0 + ecb + 32];
  float4 ebv2 = *(const float4*)&bias[c0 + ecb + 64];
  float4 ebv3 = *(const float4*)&bias[c0 + ecb + 96];

  // transpose accumulators to row-major f32 tiles in LDS
#pragma unroll
  for (int m = 0; m < 2; ++m)
#pragma unroll
    for (int n = 0; n < 2; ++n)
#pragma unroll
      for (int r = 0; r < 4; ++r) {
        const int rr = m * 16 + q * 4 + r;
        const int cc = w * 32 + n * 16 + ln;
        sH[rr * 132 + cc] = accH[m][n][r];
        sG[rr * 132 + cc] = accG[m][n][r];
      }
  __syncthreads();

  float rsum = 0.f, ssum = 0.f;
#define EPI(J, XV, DV, BV) \
  { \
    const int cc = ecb + (J) * 32; \
    float4 hv = *(const float4*)&sH[erow * 132 + cc]; \
    float4 gv = *(const float4*)&sG[erow * 132 + cc]; \
    f32x4 xh = {hv.x + BV.x, hv.y + BV.y, hv.z + BV.z, hv.w + BV.w}; \
    __builtin_nontemporal_store(xh, (f32x4*)&xhat[gbase + (J) * 32]); \
    float e; \
    e = XV.x - xh[0]; rsum = fmaf(e, e, rsum); \
    e = XV.y - xh[1]; rsum = fmaf(e, e, rsum); \
    e = XV.z - xh[2]; rsum = fmaf(e, e, rsum); \
    e = XV.w - xh[3]; rsum = fmaf(e, e, rsum); \
    e = DV.x - gv.x; ssum = fmaf(e, e, ssum); \
    e = DV.y - gv.y; ssum = fmaf(e, e, ssum); \
    e = DV.z - gv.z; ssum = fmaf(e, e, ssum); \
    e = DV.w - gv.w; ssum = fmaf(e, e, ssum); \
  }
  EPI(0, exv0, edv0, ebv0)
  EPI(1, exv1, edv1, ebv1)
  EPI(2, exv2, edv2, ebv2)
  EPI(3, exv3, edv3, ebv3)
#undef EPI

#pragma unroll
  for (int off = 32; off > 0; off >>= 1) {
    rsum += __shfl_down(rsum, off);
    ssum += __shfl_down(ssum, off);
  }
  if (L == 0) { red[w * 2] = rsum; red[w * 2 + 1] = ssum; }
  __syncthreads();
  if (t == 0) {
    const int bid = blockIdx.y * gridDim.x + blockIdx.x;
    pr[bid] = red[0] + red[2] + red[4] + red[6];
    ps[bid] = red[1] + red[3] + red[5] + red[7];
  }
}

// ---------------------------------------------------------------------------
// K5: reduce all partials + write the 6 scalar outputs
// ---------------------------------------------------------------------------
__global__ __launch_bounds__(256) void finalize_kernel(
    const float* __restrict__ pr, const float* __restrict__ ps,
    const float* __restrict__ pe0, const float* __restrict__ pe1,
    const float* __restrict__ pe2, const float* __restrict__ coef,
    float* __restrict__ outp)
{
  __shared__ float sred[4][5];
  const int t = threadIdx.x, L = t & 63, w = t >> 6;
  float s[5] = {0.f, 0.f, 0.f, 0.f, 0.f};
  for (int i = t; i < 2048; i += 256) {   // pr/ps: 8192 floats
    float4 a = *(const float4*)&pr[i * 4];
    float4 b = *(const float4*)&ps[i * 4];
    s[0] += a.x + a.y + a.z + a.w;
    s[1] += b.x + b.y + b.z + b.w;
  }
  if (t < 256) {                           // pe*: 1024 floats
    float4 a = *(const float4*)&pe0[t * 4];
    float4 b = *(const float4*)&pe1[t * 4];
    float4 c = *(const float4*)&pe2[t * 4];
    s[2] += a.x + a.y + a.z + a.w;
    s[3] += b.x + b.y + b.z + b.w;
    s[4] += c.x + c.y + c.z + c.w;
  }
#pragma unroll
  for (int off = 32; off > 0; off >>= 1)
#pragma unroll
    for (int k = 0; k < 5; ++k) s[k] += __shfl_down(s[k], off);
  if (L == 0)
#pragma unroll
    for (int k = 0; k < 5; ++k) sred[w][k] = s[k];
  __syncthreads();
  if (t == 0) {
    float r[5];
#pragma unroll
    for (int k = 0; k < 5; ++k)
      r[k] = sred[0][k] + sred[1][k] + sred[2][k] + sred[3][k];
    outp[0] = r[2] * (1.0f / 16384.0f);      // loss_po
    outp[1] = r[3] * (1.0f / 16384.0f);      // loss_tr
    outp[2] = r[0] * (1.0f / 33554432.0f);   // recon
    outp[3] = r[1] * (1.0f / 33554432.0f);   // sindy_x
    outp[4] = r[4] * (1.0f / 49152.0f);      // sindy_z
    float l1 = 0.f;
    for (int i = 0; i < 21; ++i) l1 += fabsf(coef[i]);
    outp[5] = l1 * (1.0f / 21.0f);
  }
}

extern "C" void kernel_launch(void* const* d_in, const int* in_sizes, int n_in,
                              void* d_out, int out_size, void* d_ws, size_t ws_size,
                              hipStream_t stream) {
  (void)in_sizes; (void)n_in; (void)out_size; (void)ws_size;
  const float* x    = (const float*)d_in[0];
  const float* xd   = (const float*)d_in[1];
  const float* tr   = (const float*)d_in[2];
  const float* sz   = (const float*)d_in[3];
  const float* eW1  = (const float*)d_in[4];
  const float* eb1  = (const float*)d_in[5];
  const float* eW2  = (const float*)d_in[6];
  const float* eb2  = (const float*)d_in[7];
  const float* eW3  = (const float*)d_in[8];
  const float* eb3  = (const float*)d_in[9];
  const float* eW4  = (const float*)d_in[10];
  const float* eb4  = (const float*)d_in[11];
  const float* dW1  = (const float*)d_in[12];
  const float* db1  = (const float*)d_in[13];
  const float* dW2  = (const float*)d_in[14];
  const float* db2  = (const float*)d_in[15];
  const float* dW3  = (const float*)d_in[16];
  const float* db3  = (const float*)d_in[17];
  const float* dW4  = (const float*)d_in[18];
  const float* db4  = (const float*)d_in[19];
  const float* coef = (const float*)d_in[20];

  float* ws = (float*)d_ws;
  float* a1   = ws;                                       // 2097152 f32
  float* dz1  = ws + 2097152;                             // 2097152 f32
  float* zdp  = ws + 4194304;                             // 49152 f32
  unsigned short* h3b = (unsigned short*)(ws + 4243472);  // 2097152 bf16
  unsigned short* g3b = (unsigned short*)(ws + 5292048);  // 2097152 bf16
  unsigned short* Wb1 = (unsigned short*)(ws + 6340624);  // 262144 bf16
  unsigned short* Wb4 = (unsigned short*)(ws + 6471696);  // 262144 bf16
  // partial-sum arrays alias the Wb1 region (dead after enc1_mfma)
  float* pr  = ws + 6340624;                              // 8192 f32
  float* ps  = ws + 6348816;                              // 8192 f32
  float* pe0 = ws + 6357008;                              // 1024 f32
  float* pe1 = ws + 6361104;                              // 1024 f32
  float* pe2 = ws + 6365200;                              // 1024 f32

  float* z_out = (float*)d_out;                           // 16384*3
  float* xhat  = (float*)d_out + 49152;                   // 16384*2048
  float* scal  = (float*)d_out + 49152 + 33554432;        // 6 scalars

  wcvt_kernel<<<1024, 256, 0, stream>>>(eW1, dW4, Wb1, Wb4);
  enc1_mfma<<<1024, 512, 0, stream>>>(x, xd, tr, Wb1, eW1, eb1, a1, dz1);
  enc_small_kernel<<<1024, 256, 0, stream>>>(a1, dz1, eW2, eb2, eW3, eb3, eW4, eb4,
                                             coef, sz, tr, z_out, zdp, pe0, pe1, pe2);
  dec_small_kernel<<<1024, 256, 0, stream>>>(z_out, zdp, dW1, db1, dW2, db2, dW3, db3,
                                             h3b, g3b);
  dim3 g4(512, 16);
  dec4_mfma<<<g4, 256, 0, stream>>>(h3b, g3b, Wb4, db4, x, xd, xhat, pr, ps);
  finalize_kernel<<<1, 256, 0, stream>>>(pr, ps, pe0, pe1, pe2, coef, scal);
}

// Round 5
// 522.555 us; speedup vs baseline: 1.2025x; 1.2025x over previous
//
#include <hip/hip_runtime.h>
#include <hip/hip_bf16.h>
#include <math.h>

typedef __attribute__((ext_vector_type(8))) short short8;
typedef __attribute__((ext_vector_type(4))) float f32x4;

__device__ __forceinline__ float sigm(float v) { return 1.0f / (1.0f + expf(-v)); }
__device__ __forceinline__ unsigned short f2b(float f) {
  __hip_bfloat16 h = __float2bfloat16(f);
  return __builtin_bit_cast(unsigned short, h);
}
__device__ __forceinline__ void gload16(const void* g, void* l) {
  __builtin_amdgcn_global_load_lds(
      (const __attribute__((address_space(1))) unsigned int*)g,
      (__attribute__((address_space(3))) unsigned int*)l, 16, 0, 0);
}
__device__ __forceinline__ short8 pack8(float4 a, float4 b) {
  short8 r;
  r[0] = (short)f2b(a.x); r[1] = (short)f2b(a.y);
  r[2] = (short)f2b(a.z); r[3] = (short)f2b(a.w);
  r[4] = (short)f2b(b.x); r[5] = (short)f2b(b.y);
  r[6] = (short)f2b(b.z); r[7] = (short)f2b(b.w);
  return r;
}

// ---------------------------------------------------------------------------
// K0: pre-convert eW1[:, :2048] -> Wb1 bf16 [128][2048], dW4 -> Wb4 bf16 [2048][128]
// ---------------------------------------------------------------------------
__global__ __launch_bounds__(256) void wcvt_kernel(
    const float* __restrict__ eW1, const float* __restrict__ dW4,
    unsigned short* __restrict__ Wb1, unsigned short* __restrict__ Wb4)
{
  int idx = blockIdx.x * 256 + threadIdx.x;   // 0..262143
  int o = idx >> 11, k = idx & 2047;
  Wb1[idx] = f2b(eW1[(size_t)o * 2049 + k]);
  Wb4[idx] = f2b(dW4[idx]);
}

// ---------------------------------------------------------------------------
// K1: MFMA dual GEMM: accx = x@W.T, accd = xd@W.T (bf16 mfma, fp32 acc)
// v5: m97-style. BM=32, BK=64, 256 thr. global_load_lds (16B) coalesced
// staging of A/D (f32) + W (bf16) into double-buffered LDS; linear LDS dest,
// inverse-XOR-swizzled global source, swizzled ds_read (2-way conflicts).
// 2-phase pipeline: STAGE(t+1) || compute(t), one barrier per tile.
// ---------------------------------------------------------------------------
__global__ __launch_bounds__(256) void enc1_mfma(
    const float* __restrict__ x, const float* __restrict__ xd,
    const float* __restrict__ tr, const unsigned short* __restrict__ Wb,
    const float* __restrict__ Wfull, const float* __restrict__ bias,
    float* __restrict__ a1, float* __restrict__ dz1)
{
  // per buffer (32KB): A f32[32][64] @0 (8KB), D f32[32][64] @8192, W bf16[128][64] @16384 (16KB)
  __shared__ __align__(16) char sm[65536];
  const int t = threadIdx.x;
  const int w = t >> 6, L = t & 63, q = L >> 4, ln = L & 15;
  const int r0 = blockIdx.x * 32;

  // staging source mappings (inverse of the read-side XOR swizzle)
  const int arow  = t >> 4;                               // 0..15
  const int acolf = (((t & 15) ^ arow) & 15) << 2;        // float offset in [0,64)
  const int wrow  = t >> 3;                               // 0..31
  const int wcols = (((t & 7) ^ (wrow & 7)) & 7) << 3;    // short offset in [0,64)
  const float* xsrc = x  + (size_t)(r0 + arow) * 2048 + acolf;
  const float* dsrc = xd + (size_t)(r0 + arow) * 2048 + acolf;
  const unsigned short* wsrc = Wb + (size_t)wrow * 2048 + wcols;
  const int wb = (t >> 6) << 10;                          // wave-uniform LDS sub-base

#define STAGE(c, kt) { \
    const int kb = (kt) * 64; \
    char* bA_ = sm + (c) * 32768; \
    gload16(xsrc + kb,          bA_ + wb); \
    gload16(xsrc + kb + 32768,  bA_ + wb + 4096); \
    gload16(dsrc + kb,          bA_ + 8192 + wb); \
    gload16(dsrc + kb + 32768,  bA_ + 8192 + wb + 4096); \
    gload16(wsrc + kb,          bA_ + 16384 + wb); \
    gload16(wsrc + kb + 65536,  bA_ + 16384 + wb + 4096); \
    gload16(wsrc + kb + 131072, bA_ + 16384 + wb + 8192); \
    gload16(wsrc + kb + 196608, bA_ + 16384 + wb + 12288); }

  f32x4 accx[2][2], accd[2][2];
#pragma unroll
  for (int m = 0; m < 2; ++m)
#pragma unroll
    for (int n = 0; n < 2; ++n) {
      accx[m][n] = (f32x4){0.f, 0.f, 0.f, 0.f};
      accd[m][n] = (f32x4){0.f, 0.f, 0.f, 0.f};
    }

  STAGE(0, 0)
  __syncthreads();
  for (int kt = 0; kt < 32; ++kt) {
    if (kt + 1 < 32) STAGE((kt + 1) & 1, kt + 1)
    const char* bA = sm + (kt & 1) * 32768;
    const char* bD = bA + 8192;
    const char* bW = bA + 16384;
#pragma unroll
    for (int ks = 0; ks < 2; ++ks) {
      short8 ax[2], ad[2], bw[2];
#pragma unroll
      for (int m = 0; m < 2; ++m) {
        const int rowb = (m * 16 + ln) * 256;
        const int off = ks * 128 + q * 32;
        float4 lo  = *(const float4*)(bA + rowb + ((off     ) ^ (ln << 4)));
        float4 hi  = *(const float4*)(bA + rowb + ((off + 16) ^ (ln << 4)));
        float4 dlo = *(const float4*)(bD + rowb + ((off     ) ^ (ln << 4)));
        float4 dhi = *(const float4*)(bD + rowb + ((off + 16) ^ (ln << 4)));
        ax[m] = pack8(lo, hi);
        ad[m] = pack8(dlo, dhi);
      }
#pragma unroll
      for (int n = 0; n < 2; ++n) {
        const int row = w * 32 + n * 16 + ln;
        const int off = ks * 64 + q * 16;
        bw[n] = *(const short8*)(bW + row * 128 + (off ^ ((ln & 7) << 4)));
      }
#pragma unroll
      for (int m = 0; m < 2; ++m)
#pragma unroll
        for (int n = 0; n < 2; ++n) {
          accx[m][n] = __builtin_amdgcn_mfma_f32_16x16x32_bf16(ax[m], bw[n], accx[m][n], 0, 0, 0);
          accd[m][n] = __builtin_amdgcn_mfma_f32_16x16x32_bf16(ad[m], bw[n], accd[m][n], 0, 0, 0);
        }
    }
    __syncthreads();
  }
#undef STAGE

  // epilogue: C[row = m*16 + q*4 + r][col = w*32 + n*16 + ln]
#pragma unroll
  for (int m = 0; m < 2; ++m) {
#pragma unroll
    for (int r = 0; r < 4; ++r) {
      const int row = r0 + m * 16 + q * 4 + r;
      const float trv = tr[row];
#pragma unroll
      for (int n = 0; n < 2; ++n) {
        const int col = w * 32 + n * 16 + ln;
        const float wl = Wfull[(size_t)col * 2049 + 2048];
        float p = accx[m][n][r] + trv * wl + bias[col];
        float g = accd[m][n][r] + trv * wl;
        float a = sigm(p);
        a1 [(size_t)row * 128 + col] = a;
        dz1[(size_t)row * 128 + col] = a * (1.f - a) * g;
      }
    }
  }
}

// ---------------------------------------------------------------------------
// K2: encoder layers 2-4. 16 rows/block, k-outer multi-accumulator loops.
// ---------------------------------------------------------------------------
__global__ __launch_bounds__(256) void enc_small_kernel(
    const float* __restrict__ a1, const float* __restrict__ dz1,
    const float* __restrict__ W2, const float* __restrict__ b2,
    const float* __restrict__ W3, const float* __restrict__ b3,
    const float* __restrict__ W4, const float* __restrict__ b4,
    const float* __restrict__ coef, const float* __restrict__ size_in,
    const float* __restrict__ treat,
    float* __restrict__ z_out, float* __restrict__ zdp_out,
    float* __restrict__ pe0, float* __restrict__ pe1, float* __restrict__ pe2)
{
  __shared__ float sW2[64 * 129];
  __shared__ float sW3[32 * 65];
  __shared__ float sW4[96];
  __shared__ float sB2[64], sB3[32], sB4[3], sC[21];
  __shared__ __align__(16) float a1s[16 * 128], d1s[16 * 128];
  __shared__ float a2s[16 * 64],  d2s[16 * 64];
  __shared__ float a3s[16 * 32],  d3s[16 * 32];
  __shared__ float zs[48], zds[48];
  __shared__ float rowl[16][3];
  const int t = threadIdx.x;
  for (int i = t; i < 64 * 128; i += 256) sW2[(i >> 7) * 129 + (i & 127)] = W2[i];
  for (int i = t; i < 32 * 64;  i += 256) sW3[(i >> 6) * 65  + (i & 63)]  = W3[i];
  if (t < 96) sW4[t] = W4[t];
  if (t < 64) sB2[t] = b2[t];
  if (t < 32) sB3[t] = b3[t];
  if (t < 3)  sB4[t] = b4[t];
  if (t < 21) sC[t]  = coef[t];
  const int r0 = blockIdx.x * 16;
  {
    const float4* a1g = (const float4*)(a1  + (size_t)r0 * 128);
    const float4* d1g = (const float4*)(dz1 + (size_t)r0 * 128);
    float4* a1s4 = (float4*)a1s;
    float4* d1s4 = (float4*)d1s;
#pragma unroll
    for (int i = 0; i < 2; ++i) {
      a1s4[t + i * 256] = a1g[t + i * 256];
      d1s4[t + i * 256] = d1g[t + i * 256];
    }
  }
  __syncthreads();
  {
    const int o = t & 63, rb = t >> 6;
    float p[4] = {0.f, 0.f, 0.f, 0.f}, g[4] = {0.f, 0.f, 0.f, 0.f};
#pragma unroll 4
    for (int k = 0; k < 128; ++k) {
      const float wv = sW2[o * 129 + k];
#pragma unroll
      for (int u = 0; u < 4; ++u) {
        p[u] = fmaf(wv, a1s[(rb + u * 4) * 128 + k], p[u]);
        g[u] = fmaf(wv, d1s[(rb + u * 4) * 128 + k], g[u]);
      }
    }
#pragma unroll
    for (int u = 0; u < 4; ++u) {
      float a = sigm(p[u] + sB2[o]);
      a2s[(rb + u * 4) * 64 + o] = a;
      d2s[(rb + u * 4) * 64 + o] = a * (1.f - a) * g[u];
    }
  }
  __syncthreads();
  {
    const int o = t & 31, r3 = t >> 5;
    float p[2] = {0.f, 0.f}, g[2] = {0.f, 0.f};
#pragma unroll 4
    for (int k = 0; k < 64; ++k) {
      const float wv = sW3[o * 65 + k];
#pragma unroll
      for (int u = 0; u < 2; ++u) {
        p[u] = fmaf(wv, a2s[(r3 + u * 8) * 64 + k], p[u]);
        g[u] = fmaf(wv, d2s[(r3 + u * 8) * 64 + k], g[u]);
      }
    }
#pragma unroll
    for (int u = 0; u < 2; ++u) {
      float a = sigm(p[u] + sB3[o]);
      a3s[(r3 + u * 8) * 32 + o] = a;
      d3s[(r3 + u * 8) * 32 + o] = a * (1.f - a) * g[u];
    }
  }
  __syncthreads();
  if (t < 48) {
    const int r = t / 3, j = t % 3;
    float p = 0.f, g = 0.f;
#pragma unroll
    for (int k = 0; k < 32; ++k) {
      float wv = sW4[j * 32 + k];
      p = fmaf(wv, a3s[r * 32 + k], p);
      g = fmaf(wv, d3s[r * 32 + k], g);
    }
    float zv = p + sB4[j];
    zs [r * 3 + j] = zv;
    zds[r * 3 + j] = g;
    z_out[(size_t)(r0 + r) * 3 + j] = zv;
  }
  __syncthreads();
  if (t < 16) {
    const int r = t;
    float s = zs[r * 3 + 0], d = zs[r * 3 + 1], tt = zs[r * 3 + 2];
    float th[7] = {1.f, s, s * s, s * d, s * tt, s * s * d, s * s * tt};
    float sz = 0.f;
    for (int j = 0; j < 3; ++j) {
      float zp = 0.f;
#pragma unroll
      for (int i = 0; i < 7; ++i) zp = fmaf(th[i], sC[i * 3 + j], zp);
      zdp_out[(size_t)(r0 + r) * 3 + j] = zp;
      float e = zds[r * 3 + j] - zp;
      sz += e * e;
    }
    float e0 = s - size_in[r0 + r];
    float logit = tt;
    float trv = treat[r0 + r];
    float lt = fmaxf(logit, 0.f) + log1pf(expf(-fabsf(logit))) - logit * trv;
    rowl[r][0] = e0 * e0; rowl[r][1] = lt; rowl[r][2] = sz;
  }
  __syncthreads();
  if (t == 0) {
    float s0 = 0, s1 = 0, s2 = 0;
    for (int r = 0; r < 16; ++r) { s0 += rowl[r][0]; s1 += rowl[r][1]; s2 += rowl[r][2]; }
    pe0[blockIdx.x] = s0;
    pe1[blockIdx.x] = s1;
    pe2[blockIdx.x] = s2;
  }
}

// ---------------------------------------------------------------------------
// K3: decoder layers 1-3. 16 rows/block, k-outer multi-accumulator loops.
// ---------------------------------------------------------------------------
__global__ __launch_bounds__(256) void dec_small_kernel(
    const float* __restrict__ z_in, const float* __restrict__ zdp,
    const float* __restrict__ W1, const float* __restrict__ b1,
    const float* __restrict__ W2, const float* __restrict__ b2,
    const float* __restrict__ W3, const float* __restrict__ b3,
    unsigned short* __restrict__ h3b, unsigned short* __restrict__ g3b)
{
  __shared__ float sW1[96], sB1[32];
  __shared__ float sW2[64 * 33], sB2[64];
  __shared__ float sW3[128 * 65], sB3[128];
  __shared__ float zr[48], zp[48];
  __shared__ float h1s[16 * 32], g1s[16 * 32];
  __shared__ float h2s[16 * 64], g2s[16 * 64];
  const int t = threadIdx.x;
  for (int i = t; i < 64 * 32;  i += 256) sW2[(i >> 5) * 33 + (i & 31)] = W2[i];
  for (int i = t; i < 128 * 64; i += 256) sW3[(i >> 6) * 65 + (i & 63)] = W3[i];
  if (t < 96)  sW1[t] = W1[t];
  if (t < 32)  sB1[t] = b1[t];
  if (t < 64)  sB2[t] = b2[t];
  if (t < 128) sB3[t] = b3[t];
  const int r0 = blockIdx.x * 16;
  if (t < 48) { zr[t] = z_in[(size_t)r0 * 3 + t]; zp[t] = zdp[(size_t)r0 * 3 + t]; }
  __syncthreads();
  {
    const int o = t & 31, rb = t >> 5;
    float p[2], g[2];
#pragma unroll
    for (int u = 0; u < 2; ++u) {
      const int r = rb + u * 8;
      float pp = sB1[o], gg = 0.f;
#pragma unroll
      for (int k = 0; k < 3; ++k) {
        float wv = sW1[o * 3 + k];
        pp = fmaf(wv, zr[r * 3 + k], pp);
        gg = fmaf(wv, zp[r * 3 + k], gg);
      }
      p[u] = pp; g[u] = gg;
    }
#pragma unroll
    for (int u = 0; u < 2; ++u) {
      const int r = rb + u * 8;
      float h = sigm(p[u]);
      h1s[r * 32 + o] = h; g1s[r * 32 + o] = h * (1.f - h) * g[u];
    }
  }
  __syncthreads();
  {
    const int o = t & 63, rb = t >> 6;
    float p[4], g[4];
#pragma unroll
    for (int u = 0; u < 4; ++u) { p[u] = sB2[o]; g[u] = 0.f; }
#pragma unroll 4
    for (int k = 0; k < 32; ++k) {
      const float wv = sW2[o * 33 + k];
#pragma unroll
      for (int u = 0; u < 4; ++u) {
        p[u] = fmaf(wv, h1s[(rb + u * 4) * 32 + k], p[u]);
        g[u] = fmaf(wv, g1s[(rb + u * 4) * 32 + k], g[u]);
      }
    }
#pragma unroll
    for (int u = 0; u < 4; ++u) {
      float h = sigm(p[u]);
      h2s[(rb + u * 4) * 64 + o] = h;
      g2s[(rb + u * 4) * 64 + o] = h * (1.f - h) * g[u];
    }
  }
  __syncthreads();
  {
    const int o = t & 127, rb2 = t >> 7;
    float p[8], g[8];
#pragma unroll
    for (int u = 0; u < 8; ++u) { p[u] = sB3[o]; g[u] = 0.f; }
#pragma unroll 4
    for (int k = 0; k < 64; ++k) {
      const float wv = sW3[o * 65 + k];
#pragma unroll
      for (int u = 0; u < 8; ++u) {
        p[u] = fmaf(wv, h2s[(rb2 + u * 2) * 64 + k], p[u]);
        g[u] = fmaf(wv, g2s[(rb2 + u * 2) * 64 + k], g[u]);
      }
    }
#pragma unroll
    for (int u = 0; u < 8; ++u) {
      const int r = rb2 + u * 2;
      float h = sigm(p[u]);
      h3b[(size_t)(r0 + r) * 128 + o] = f2b(h);
      g3b[(size_t)(r0 + r) * 128 + o] = f2b(h * (1.f - h) * g[u]);
    }
  }
}

// ---------------------------------------------------------------------------
// K4: MFMA dual GEMM: xhat = h3@W4.T + b, xdp = g3@W4.T; fused recon/sindy_x.
// Early-issued epilogue loads; float4 epilogue; per-block partial sums.
// ---------------------------------------------------------------------------
__global__ __launch_bounds__(256, 2) void dec4_mfma(
    const unsigned short* __restrict__ h3b, const unsigned short* __restrict__ g3b,
    const unsigned short* __restrict__ Wb, const float* __restrict__ bias,
    const float* __restrict__ x, const float* __restrict__ xd,
    float* __restrict__ xhat, float* __restrict__ pr, float* __restrict__ ps)
{
  __shared__ float sH[32 * 132];
  __shared__ float sG[32 * 132];
  __shared__ float red[8];
  const int t = threadIdx.x, w = t >> 6, L = t & 63, q = L >> 4, ln = L & 15;
  const int r0 = blockIdx.x * 32, c0 = blockIdx.y * 128;

  f32x4 accH[2][2], accG[2][2];
#pragma unroll
  for (int m = 0; m < 2; ++m)
#pragma unroll
    for (int n = 0; n < 2; ++n) {
      accH[m][n] = (f32x4){0.f, 0.f, 0.f, 0.f};
      accG[m][n] = (f32x4){0.f, 0.f, 0.f, 0.f};
    }

  const size_t a0 = (size_t)(r0 + ln) * 128;
  const size_t a1r = (size_t)(r0 + 16 + ln) * 128;
  const size_t b0 = (size_t)(c0 + w * 32 + ln) * 128;
  const size_t b1 = (size_t)(c0 + w * 32 + 16 + ln) * 128;

#pragma unroll
  for (int ks = 0; ks < 4; ++ks) {
    const int kb = ks * 32 + q * 8;
    short8 ah0 = *(const short8*)&h3b[a0 + kb];
    short8 ah1 = *(const short8*)&h3b[a1r + kb];
    short8 ag0 = *(const short8*)&g3b[a0 + kb];
    short8 ag1 = *(const short8*)&g3b[a1r + kb];
    short8 bw0 = *(const short8*)&Wb[b0 + kb];
    short8 bw1 = *(const short8*)&Wb[b1 + kb];
    accH[0][0] = __builtin_amdgcn_mfma_f32_16x16x32_bf16(ah0, bw0, accH[0][0], 0, 0, 0);
    accH[0][1] = __builtin_amdgcn_mfma_f32_16x16x32_bf16(ah0, bw1, accH[0][1], 0, 0, 0);
    accH[1][0] = __builtin_amdgcn_mfma_f32_16x16x32_bf16(ah1, bw0, accH[1][0], 0, 0, 0);
    accH[1][1] = __builtin_amdgcn_mfma_f32_16x16x32_bf16(ah1, bw1, accH[1][1], 0, 0, 0);
    accG[0][0] = __builtin_amdgcn_mfma_f32_16x16x32_bf16(ag0, bw0, accG[0][0], 0, 0, 0);
    accG[0][1] = __builtin_amdgcn_mfma_f32_16x16x32_bf16(ag0, bw1, accG[0][1], 0, 0, 0);
    accG[1][0] = __builtin_amdgcn_mfma_f32_16x16x32_bf16(ag1, bw0, accG[1][0], 0, 0, 0);
    accG[1][1] = __builtin_amdgcn_mfma_f32_16x16x32_bf16(ag1, bw1, accG[1][1], 0, 0, 0);
  }

  const int erow = t >> 3;
  const int ecb = (t & 7) * 4;
  const size_t gbase = (size_t)(r0 + erow) * 2048 + c0 + ecb;
  float4 exv0 = *(const float4*)&x [gbase];
  float4 exv1 = *(const float4*)&x [gbase + 32];
  float4 exv2 = *(const float4*)&x [gbase + 64];
  float4 exv3 = *(const float4*)&x [gbase + 96];
  float4 edv0 = *(const float4*)&xd[gbase];
  float4 edv1 = *(const float4*)&xd[gbase + 32];
  float4 edv2 = *(const float4*)&xd[gbase + 64];
  float4 edv3 = *(const float4*)&xd[gbase + 96];
  float4 ebv0 = *(const float4*)&bias[c0 + ecb];
  float4 ebv1 = *(const float4*)&bias[c0 + ecb + 32];
  float4 ebv2 = *(const float4*)&bias[c0 + ecb + 64];
  float4 ebv3 = *(const float4*)&bias[c0 + ecb + 96];

#pragma unroll
  for (int m = 0; m < 2; ++m)
#pragma unroll
    for (int n = 0; n < 2; ++n)
#pragma unroll
      for (int r = 0; r < 4; ++r) {
        const int rr = m * 16 + q * 4 + r;
        const int cc = w * 32 + n * 16 + ln;
        sH[rr * 132 + cc] = accH[m][n][r];
        sG[rr * 132 + cc] = accG[m][n][r];
      }
  __syncthreads();

  float rsum = 0.f, ssum = 0.f;
#define EPI(J, XV, DV, BV) \
  { \
    const int cc = ecb + (J) * 32; \
    float4 hv = *(const float4*)&sH[erow * 132 + cc]; \
    float4 gv = *(const float4*)&sG[erow * 132 + cc]; \
    f32x4 xh = {hv.x + BV.x, hv.y + BV.y, hv.z + BV.z, hv.w + BV.w}; \
    __builtin_nontemporal_store(xh, (f32x4*)&xhat[gbase + (J) * 32]); \
    float e; \
    e = XV.x - xh[0]; rsum = fmaf(e, e, rsum); \
    e = XV.y - xh[1]; rsum = fmaf(e, e, rsum); \
    e = XV.z - xh[2]; rsum = fmaf(e, e, rsum); \
    e = XV.w - xh[3]; rsum = fmaf(e, e, rsum); \
    e = DV.x - gv.x; ssum = fmaf(e, e, ssum); \
    e = DV.y - gv.y; ssum = fmaf(e, e, ssum); \
    e = DV.z - gv.z; ssum = fmaf(e, e, ssum); \
    e = DV.w - gv.w; ssum = fmaf(e, e, ssum); \
  }
  EPI(0, exv0, edv0, ebv0)
  EPI(1, exv1, edv1, ebv1)
  EPI(2, exv2, edv2, ebv2)
  EPI(3, exv3, edv3, ebv3)
#undef EPI

#pragma unroll
  for (int off = 32; off > 0; off >>= 1) {
    rsum += __shfl_down(rsum, off);
    ssum += __shfl_down(ssum, off);
  }
  if (L == 0) { red[w * 2] = rsum; red[w * 2 + 1] = ssum; }
  __syncthreads();
  if (t == 0) {
    const int bid = blockIdx.y * gridDim.x + blockIdx.x;
    pr[bid] = red[0] + red[2] + red[4] + red[6];
    ps[bid] = red[1] + red[3] + red[5] + red[7];
  }
}

// ---------------------------------------------------------------------------
// K5: reduce all partials + write the 6 scalar outputs
// ---------------------------------------------------------------------------
__global__ __launch_bounds__(256) void finalize_kernel(
    const float* __restrict__ pr, const float* __restrict__ ps,
    const float* __restrict__ pe0, const float* __restrict__ pe1,
    const float* __restrict__ pe2, const float* __restrict__ coef,
    float* __restrict__ outp)
{
  __shared__ float sred[4][5];
  const int t = threadIdx.x, L = t & 63, w = t >> 6;
  float s[5] = {0.f, 0.f, 0.f, 0.f, 0.f};
  for (int i = t; i < 2048; i += 256) {   // pr/ps: 8192 floats
    float4 a = *(const float4*)&pr[i * 4];
    float4 b = *(const float4*)&ps[i * 4];
    s[0] += a.x + a.y + a.z + a.w;
    s[1] += b.x + b.y + b.z + b.w;
  }
  if (t < 256) {                           // pe*: 1024 floats
    float4 a = *(const float4*)&pe0[t * 4];
    float4 b = *(const float4*)&pe1[t * 4];
    float4 c = *(const float4*)&pe2[t * 4];
    s[2] += a.x + a.y + a.z + a.w;
    s[3] += b.x + b.y + b.z + b.w;
    s[4] += c.x + c.y + c.z + c.w;
  }
#pragma unroll
  for (int off = 32; off > 0; off >>= 1)
#pragma unroll
    for (int k = 0; k < 5; ++k) s[k] += __shfl_down(s[k], off);
  if (L == 0)
#pragma unroll
    for (int k = 0; k < 5; ++k) sred[w][k] = s[k];
  __syncthreads();
  if (t == 0) {
    float r[5];
#pragma unroll
    for (int k = 0; k < 5; ++k)
      r[k] = sred[0][k] + sred[1][k] + sred[2][k] + sred[3][k];
    outp[0] = r[2] * (1.0f / 16384.0f);      // loss_po
    outp[1] = r[3] * (1.0f / 16384.0f);      // loss_tr
    outp[2] = r[0] * (1.0f / 33554432.0f);   // recon
    outp[3] = r[1] * (1.0f / 33554432.0f);   // sindy_x
    outp[4] = r[4] * (1.0f / 49152.0f);      // sindy_z
    float l1 = 0.f;
    for (int i = 0; i < 21; ++i) l1 += fabsf(coef[i]);
    outp[5] = l1 * (1.0f / 21.0f);
  }
}

extern "C" void kernel_launch(void* const* d_in, const int* in_sizes, int n_in,
                              void* d_out, int out_size, void* d_ws, size_t ws_size,
                              hipStream_t stream) {
  (void)in_sizes; (void)n_in; (void)out_size; (void)ws_size;
  const float* x    = (const float*)d_in[0];
  const float* xd   = (const float*)d_in[1];
  const float* tr   = (const float*)d_in[2];
  const float* sz   = (const float*)d_in[3];
  const float* eW1  = (const float*)d_in[4];
  const float* eb1  = (const float*)d_in[5];
  const float* eW2  = (const float*)d_in[6];
  const float* eb2  = (const float*)d_in[7];
  const float* eW3  = (const float*)d_in[8];
  const float* eb3  = (const float*)d_in[9];
  const float* eW4  = (const float*)d_in[10];
  const float* eb4  = (const float*)d_in[11];
  const float* dW1  = (const float*)d_in[12];
  const float* db1  = (const float*)d_in[13];
  const float* dW2  = (const float*)d_in[14];
  const float* db2  = (const float*)d_in[15];
  const float* dW3  = (const float*)d_in[16];
  const float* db3  = (const float*)d_in[17];
  const float* dW4  = (const float*)d_in[18];
  const float* db4  = (const float*)d_in[19];
  const float* coef = (const float*)d_in[20];

  float* ws = (float*)d_ws;
  float* a1   = ws;                                       // 2097152 f32
  float* dz1  = ws + 2097152;                             // 2097152 f32
  float* zdp  = ws + 4194304;                             // 49152 f32
  unsigned short* h3b = (unsigned short*)(ws + 4243472);  // 2097152 bf16
  unsigned short* g3b = (unsigned short*)(ws + 5292048);  // 2097152 bf16
  unsigned short* Wb1 = (unsigned short*)(ws + 6340624);  // 262144 bf16
  unsigned short* Wb4 = (unsigned short*)(ws + 6471696);  // 262144 bf16
  // partial-sum arrays alias the Wb1 region (dead after enc1_mfma)
  float* pr  = ws + 6340624;                              // 8192 f32
  float* ps  = ws + 6348816;                              // 8192 f32
  float* pe0 = ws + 6357008;                              // 1024 f32
  float* pe1 = ws + 6361104;                              // 1024 f32
  float* pe2 = ws + 6365200;                              // 1024 f32

  float* z_out = (float*)d_out;                           // 16384*3
  float* xhat  = (float*)d_out + 49152;                   // 16384*2048
  float* scal  = (float*)d_out + 49152 + 33554432;        // 6 scalars

  wcvt_kernel<<<1024, 256, 0, stream>>>(eW1, dW4, Wb1, Wb4);
  enc1_mfma<<<512, 256, 0, stream>>>(x, xd, tr, Wb1, eW1, eb1, a1, dz1);
  enc_small_kernel<<<1024, 256, 0, stream>>>(a1, dz1, eW2, eb2, eW3, eb3, eW4, eb4,
                                             coef, sz, tr, z_out, zdp, pe0, pe1, pe2);
  dec_small_kernel<<<1024, 256, 0, stream>>>(z_out, zdp, dW1, db1, dW2, db2, dW3, db3,
                                             h3b, g3b);
  dim3 g4(512, 16);
  dec4_mfma<<<g4, 256, 0, stream>>>(h3b, g3b, Wb4, db4, x, xd, xhat, pr, ps);
  finalize_kernel<<<1, 256, 0, stream>>>(pr, ps, pe0, pe1, pe2, coef, scal);
}

// Round 6
// 511.915 us; speedup vs baseline: 1.2275x; 1.0208x over previous
//
#include <hip/hip_runtime.h>
#include <hip/hip_bf16.h>
#include <math.h>

typedef __attribute__((ext_vector_type(8))) short short8;
typedef __attribute__((ext_vector_type(4))) float f32x4;

__device__ __forceinline__ float sigm(float v) { return 1.0f / (1.0f + expf(-v)); }
__device__ __forceinline__ unsigned short f2b(float f) {
  __hip_bfloat16 h = __float2bfloat16(f);
  return __builtin_bit_cast(unsigned short, h);
}
__device__ __forceinline__ void gload16(const void* g, void* l) {
  __builtin_amdgcn_global_load_lds(
      (const __attribute__((address_space(1))) unsigned int*)g,
      (__attribute__((address_space(3))) unsigned int*)l, 16, 0, 0);
}
__device__ __forceinline__ short8 pack8(float4 a, float4 b) {
  short8 r;
  r[0] = (short)f2b(a.x); r[1] = (short)f2b(a.y);
  r[2] = (short)f2b(a.z); r[3] = (short)f2b(a.w);
  r[4] = (short)f2b(b.x); r[5] = (short)f2b(b.y);
  r[6] = (short)f2b(b.z); r[7] = (short)f2b(b.w);
  return r;
}

// ---------------------------------------------------------------------------
// K0: pre-convert eW1[:, :2048] -> Wb1 bf16 [128][2048], dW4 -> Wb4 bf16 [2048][128]
// ---------------------------------------------------------------------------
__global__ __launch_bounds__(256) void wcvt_kernel(
    const float* __restrict__ eW1, const float* __restrict__ dW4,
    unsigned short* __restrict__ Wb1, unsigned short* __restrict__ Wb4)
{
  int idx = blockIdx.x * 256 + threadIdx.x;   // 0..262143
  int o = idx >> 11, k = idx & 2047;
  Wb1[idx] = f2b(eW1[(size_t)o * 2049 + k]);
  Wb4[idx] = f2b(dW4[idx]);
}

// ---------------------------------------------------------------------------
// K1: MFMA dual GEMM (unchanged from r5): global_load_lds staging, dbuf,
// XOR-swizzled reads. BM=32, BK=64, 256 thr, grid 512.
// ---------------------------------------------------------------------------
__global__ __launch_bounds__(256) void enc1_mfma(
    const float* __restrict__ x, const float* __restrict__ xd,
    const float* __restrict__ tr, const unsigned short* __restrict__ Wb,
    const float* __restrict__ Wfull, const float* __restrict__ bias,
    float* __restrict__ a1, float* __restrict__ dz1)
{
  __shared__ __align__(16) char sm[65536];
  const int t = threadIdx.x;
  const int w = t >> 6, L = t & 63, q = L >> 4, ln = L & 15;
  const int r0 = blockIdx.x * 32;

  const int arow  = t >> 4;
  const int acolf = (((t & 15) ^ arow) & 15) << 2;
  const int wrow  = t >> 3;
  const int wcols = (((t & 7) ^ (wrow & 7)) & 7) << 3;
  const float* xsrc = x  + (size_t)(r0 + arow) * 2048 + acolf;
  const float* dsrc = xd + (size_t)(r0 + arow) * 2048 + acolf;
  const unsigned short* wsrc = Wb + (size_t)wrow * 2048 + wcols;
  const int wb = (t >> 6) << 10;

#define STAGE(c, kt) { \
    const int kb = (kt) * 64; \
    char* bA_ = sm + (c) * 32768; \
    gload16(xsrc + kb,          bA_ + wb); \
    gload16(xsrc + kb + 32768,  bA_ + wb + 4096); \
    gload16(dsrc + kb,          bA_ + 8192 + wb); \
    gload16(dsrc + kb + 32768,  bA_ + 8192 + wb + 4096); \
    gload16(wsrc + kb,          bA_ + 16384 + wb); \
    gload16(wsrc + kb + 65536,  bA_ + 16384 + wb + 4096); \
    gload16(wsrc + kb + 131072, bA_ + 16384 + wb + 8192); \
    gload16(wsrc + kb + 196608, bA_ + 16384 + wb + 12288); }

  f32x4 accx[2][2], accd[2][2];
#pragma unroll
  for (int m = 0; m < 2; ++m)
#pragma unroll
    for (int n = 0; n < 2; ++n) {
      accx[m][n] = (f32x4){0.f, 0.f, 0.f, 0.f};
      accd[m][n] = (f32x4){0.f, 0.f, 0.f, 0.f};
    }

  STAGE(0, 0)
  __syncthreads();
  for (int kt = 0; kt < 32; ++kt) {
    if (kt + 1 < 32) STAGE((kt + 1) & 1, kt + 1)
    const char* bA = sm + (kt & 1) * 32768;
    const char* bD = bA + 8192;
    const char* bW = bA + 16384;
#pragma unroll
    for (int ks = 0; ks < 2; ++ks) {
      short8 ax[2], ad[2], bw[2];
#pragma unroll
      for (int m = 0; m < 2; ++m) {
        const int rowb = (m * 16 + ln) * 256;
        const int off = ks * 128 + q * 32;
        float4 lo  = *(const float4*)(bA + rowb + ((off     ) ^ (ln << 4)));
        float4 hi  = *(const float4*)(bA + rowb + ((off + 16) ^ (ln << 4)));
        float4 dlo = *(const float4*)(bD + rowb + ((off     ) ^ (ln << 4)));
        float4 dhi = *(const float4*)(bD + rowb + ((off + 16) ^ (ln << 4)));
        ax[m] = pack8(lo, hi);
        ad[m] = pack8(dlo, dhi);
      }
#pragma unroll
      for (int n = 0; n < 2; ++n) {
        const int row = w * 32 + n * 16 + ln;
        const int off = ks * 64 + q * 16;
        bw[n] = *(const short8*)(bW + row * 128 + (off ^ ((ln & 7) << 4)));
      }
#pragma unroll
      for (int m = 0; m < 2; ++m)
#pragma unroll
        for (int n = 0; n < 2; ++n) {
          accx[m][n] = __builtin_amdgcn_mfma_f32_16x16x32_bf16(ax[m], bw[n], accx[m][n], 0, 0, 0);
          accd[m][n] = __builtin_amdgcn_mfma_f32_16x16x32_bf16(ad[m], bw[n], accd[m][n], 0, 0, 0);
        }
    }
    __syncthreads();
  }
#undef STAGE

#pragma unroll
  for (int m = 0; m < 2; ++m) {
#pragma unroll
    for (int r = 0; r < 4; ++r) {
      const int row = r0 + m * 16 + q * 4 + r;
      const float trv = tr[row];
#pragma unroll
      for (int n = 0; n < 2; ++n) {
        const int col = w * 32 + n * 16 + ln;
        const float wl = Wfull[(size_t)col * 2049 + 2048];
        float p = accx[m][n][r] + trv * wl + bias[col];
        float g = accd[m][n][r] + trv * wl;
        float a = sigm(p);
        a1 [(size_t)row * 128 + col] = a;
        dz1[(size_t)row * 128 + col] = a * (1.f - a) * g;
      }
    }
  }
}

// ---------------------------------------------------------------------------
// K2: encoder layers 2-4 (unchanged).
// ---------------------------------------------------------------------------
__global__ __launch_bounds__(256) void enc_small_kernel(
    const float* __restrict__ a1, const float* __restrict__ dz1,
    const float* __restrict__ W2, const float* __restrict__ b2,
    const float* __restrict__ W3, const float* __restrict__ b3,
    const float* __restrict__ W4, const float* __restrict__ b4,
    const float* __restrict__ coef, const float* __restrict__ size_in,
    const float* __restrict__ treat,
    float* __restrict__ z_out, float* __restrict__ zdp_out,
    float* __restrict__ pe0, float* __restrict__ pe1, float* __restrict__ pe2)
{
  __shared__ float sW2[64 * 129];
  __shared__ float sW3[32 * 65];
  __shared__ float sW4[96];
  __shared__ float sB2[64], sB3[32], sB4[3], sC[21];
  __shared__ __align__(16) float a1s[16 * 128], d1s[16 * 128];
  __shared__ float a2s[16 * 64],  d2s[16 * 64];
  __shared__ float a3s[16 * 32],  d3s[16 * 32];
  __shared__ float zs[48], zds[48];
  __shared__ float rowl[16][3];
  const int t = threadIdx.x;
  for (int i = t; i < 64 * 128; i += 256) sW2[(i >> 7) * 129 + (i & 127)] = W2[i];
  for (int i = t; i < 32 * 64;  i += 256) sW3[(i >> 6) * 65  + (i & 63)]  = W3[i];
  if (t < 96) sW4[t] = W4[t];
  if (t < 64) sB2[t] = b2[t];
  if (t < 32) sB3[t] = b3[t];
  if (t < 3)  sB4[t] = b4[t];
  if (t < 21) sC[t]  = coef[t];
  const int r0 = blockIdx.x * 16;
  {
    const float4* a1g = (const float4*)(a1  + (size_t)r0 * 128);
    const float4* d1g = (const float4*)(dz1 + (size_t)r0 * 128);
    float4* a1s4 = (float4*)a1s;
    float4* d1s4 = (float4*)d1s;
#pragma unroll
    for (int i = 0; i < 2; ++i) {
      a1s4[t + i * 256] = a1g[t + i * 256];
      d1s4[t + i * 256] = d1g[t + i * 256];
    }
  }
  __syncthreads();
  {
    const int o = t & 63, rb = t >> 6;
    float p[4] = {0.f, 0.f, 0.f, 0.f}, g[4] = {0.f, 0.f, 0.f, 0.f};
#pragma unroll 4
    for (int k = 0; k < 128; ++k) {
      const float wv = sW2[o * 129 + k];
#pragma unroll
      for (int u = 0; u < 4; ++u) {
        p[u] = fmaf(wv, a1s[(rb + u * 4) * 128 + k], p[u]);
        g[u] = fmaf(wv, d1s[(rb + u * 4) * 128 + k], g[u]);
      }
    }
#pragma unroll
    for (int u = 0; u < 4; ++u) {
      float a = sigm(p[u] + sB2[o]);
      a2s[(rb + u * 4) * 64 + o] = a;
      d2s[(rb + u * 4) * 64 + o] = a * (1.f - a) * g[u];
    }
  }
  __syncthreads();
  {
    const int o = t & 31, r3 = t >> 5;
    float p[2] = {0.f, 0.f}, g[2] = {0.f, 0.f};
#pragma unroll 4
    for (int k = 0; k < 64; ++k) {
      const float wv = sW3[o * 65 + k];
#pragma unroll
      for (int u = 0; u < 2; ++u) {
        p[u] = fmaf(wv, a2s[(r3 + u * 8) * 64 + k], p[u]);
        g[u] = fmaf(wv, d2s[(r3 + u * 8) * 64 + k], g[u]);
      }
    }
#pragma unroll
    for (int u = 0; u < 2; ++u) {
      float a = sigm(p[u] + sB3[o]);
      a3s[(r3 + u * 8) * 32 + o] = a;
      d3s[(r3 + u * 8) * 32 + o] = a * (1.f - a) * g[u];
    }
  }
  __syncthreads();
  if (t < 48) {
    const int r = t / 3, j = t % 3;
    float p = 0.f, g = 0.f;
#pragma unroll
    for (int k = 0; k < 32; ++k) {
      float wv = sW4[j * 32 + k];
      p = fmaf(wv, a3s[r * 32 + k], p);
      g = fmaf(wv, d3s[r * 32 + k], g);
    }
    float zv = p + sB4[j];
    zs [r * 3 + j] = zv;
    zds[r * 3 + j] = g;
    z_out[(size_t)(r0 + r) * 3 + j] = zv;
  }
  __syncthreads();
  if (t < 16) {
    const int r = t;
    float s = zs[r * 3 + 0], d = zs[r * 3 + 1], tt = zs[r * 3 + 2];
    float th[7] = {1.f, s, s * s, s * d, s * tt, s * s * d, s * s * tt};
    float sz = 0.f;
    for (int j = 0; j < 3; ++j) {
      float zp = 0.f;
#pragma unroll
      for (int i = 0; i < 7; ++i) zp = fmaf(th[i], sC[i * 3 + j], zp);
      zdp_out[(size_t)(r0 + r) * 3 + j] = zp;
      float e = zds[r * 3 + j] - zp;
      sz += e * e;
    }
    float e0 = s - size_in[r0 + r];
    float logit = tt;
    float trv = treat[r0 + r];
    float lt = fmaxf(logit, 0.f) + log1pf(expf(-fabsf(logit))) - logit * trv;
    rowl[r][0] = e0 * e0; rowl[r][1] = lt; rowl[r][2] = sz;
  }
  __syncthreads();
  if (t == 0) {
    float s0 = 0, s1 = 0, s2 = 0;
    for (int r = 0; r < 16; ++r) { s0 += rowl[r][0]; s1 += rowl[r][1]; s2 += rowl[r][2]; }
    pe0[blockIdx.x] = s0;
    pe1[blockIdx.x] = s1;
    pe2[blockIdx.x] = s2;
  }
}

// ---------------------------------------------------------------------------
// K3: decoder layers 1-3 (unchanged).
// ---------------------------------------------------------------------------
__global__ __launch_bounds__(256) void dec_small_kernel(
    const float* __restrict__ z_in, const float* __restrict__ zdp,
    const float* __restrict__ W1, const float* __restrict__ b1,
    const float* __restrict__ W2, const float* __restrict__ b2,
    const float* __restrict__ W3, const float* __restrict__ b3,
    unsigned short* __restrict__ h3b, unsigned short* __restrict__ g3b)
{
  __shared__ float sW1[96], sB1[32];
  __shared__ float sW2[64 * 33], sB2[64];
  __shared__ float sW3[128 * 65], sB3[128];
  __shared__ float zr[48], zp[48];
  __shared__ float h1s[16 * 32], g1s[16 * 32];
  __shared__ float h2s[16 * 64], g2s[16 * 64];
  const int t = threadIdx.x;
  for (int i = t; i < 64 * 32;  i += 256) sW2[(i >> 5) * 33 + (i & 31)] = W2[i];
  for (int i = t; i < 128 * 64; i += 256) sW3[(i >> 6) * 65 + (i & 63)] = W3[i];
  if (t < 96)  sW1[t] = W1[t];
  if (t < 32)  sB1[t] = b1[t];
  if (t < 64)  sB2[t] = b2[t];
  if (t < 128) sB3[t] = b3[t];
  const int r0 = blockIdx.x * 16;
  if (t < 48) { zr[t] = z_in[(size_t)r0 * 3 + t]; zp[t] = zdp[(size_t)r0 * 3 + t]; }
  __syncthreads();
  {
    const int o = t & 31, rb = t >> 5;
    float p[2], g[2];
#pragma unroll
    for (int u = 0; u < 2; ++u) {
      const int r = rb + u * 8;
      float pp = sB1[o], gg = 0.f;
#pragma unroll
      for (int k = 0; k < 3; ++k) {
        float wv = sW1[o * 3 + k];
        pp = fmaf(wv, zr[r * 3 + k], pp);
        gg = fmaf(wv, zp[r * 3 + k], gg);
      }
      p[u] = pp; g[u] = gg;
    }
#pragma unroll
    for (int u = 0; u < 2; ++u) {
      const int r = rb + u * 8;
      float h = sigm(p[u]);
      h1s[r * 32 + o] = h; g1s[r * 32 + o] = h * (1.f - h) * g[u];
    }
  }
  __syncthreads();
  {
    const int o = t & 63, rb = t >> 6;
    float p[4], g[4];
#pragma unroll
    for (int u = 0; u < 4; ++u) { p[u] = sB2[o]; g[u] = 0.f; }
#pragma unroll 4
    for (int k = 0; k < 32; ++k) {
      const float wv = sW2[o * 33 + k];
#pragma unroll
      for (int u = 0; u < 4; ++u) {
        p[u] = fmaf(wv, h1s[(rb + u * 4) * 32 + k], p[u]);
        g[u] = fmaf(wv, g1s[(rb + u * 4) * 32 + k], g[u]);
      }
    }
#pragma unroll
    for (int u = 0; u < 4; ++u) {
      float h = sigm(p[u]);
      h2s[(rb + u * 4) * 64 + o] = h;
      g2s[(rb + u * 4) * 64 + o] = h * (1.f - h) * g[u];
    }
  }
  __syncthreads();
  {
    const int o = t & 127, rb2 = t >> 7;
    float p[8], g[8];
#pragma unroll
    for (int u = 0; u < 8; ++u) { p[u] = sB3[o]; g[u] = 0.f; }
#pragma unroll 4
    for (int k = 0; k < 64; ++k) {
      const float wv = sW3[o * 65 + k];
#pragma unroll
      for (int u = 0; u < 8; ++u) {
        p[u] = fmaf(wv, h2s[(rb2 + u * 2) * 64 + k], p[u]);
        g[u] = fmaf(wv, g2s[(rb2 + u * 2) * 64 + k], g[u]);
      }
    }
#pragma unroll
    for (int u = 0; u < 8; ++u) {
      const int r = rb2 + u * 2;
      float h = sigm(p[u]);
      h3b[(size_t)(r0 + r) * 128 + o] = f2b(h);
      g3b[(size_t)(r0 + r) * 128 + o] = f2b(h * (1.f - h) * g[u]);
    }
  }
}

// ---------------------------------------------------------------------------
// K4: dec4 v4. 512 row-blocks (BM=32), each loops 16 column tiles (BN=128).
// H/G frags held in registers (loaded once). W staged via global_load_lds in
// K-half tiles (16KB), double-buffered, XOR-swizzled (linear dest + inverse-
// swizzled source). Epilogue x/xd prefetched one c-tile ahead. 3 barriers/tile.
// ---------------------------------------------------------------------------
__global__ __launch_bounds__(256, 2) void dec4_mfma(
    const unsigned short* __restrict__ h3b, const unsigned short* __restrict__ g3b,
    const unsigned short* __restrict__ Wb, const float* __restrict__ bias,
    const float* __restrict__ x, const float* __restrict__ xd,
    float* __restrict__ xhat, float* __restrict__ pr, float* __restrict__ ps)
{
  __shared__ __align__(16) char Wsm[2][16384];   // K-half W tiles (dbuf)
  __shared__ float sH[32 * 132];
  __shared__ float sG[32 * 132];
  __shared__ float red[8];
  const int t = threadIdx.x, w = t >> 6, L = t & 63, q = L >> 4, ln = L & 15;
  const int r0 = blockIdx.x * 32;

  // ---- H/G fragments: registers, loaded once per block ----
  short8 fh[2][4], fg[2][4];
  {
    const size_t a0 = (size_t)(r0 + ln) * 128;
    const size_t a1 = (size_t)(r0 + 16 + ln) * 128;
#pragma unroll
    for (int ks = 0; ks < 4; ++ks) {
      const int kb = ks * 32 + q * 8;
      fh[0][ks] = *(const short8*)&h3b[a0 + kb];
      fh[1][ks] = *(const short8*)&h3b[a1 + kb];
      fg[0][ks] = *(const short8*)&g3b[a0 + kb];
      fg[1][ks] = *(const short8*)&g3b[a1 + kb];
    }
  }

  // ---- W staging: LDS[row][s'] = global chunk s'^(row&7) (16B chunks) ----
  const int srow0 = t >> 3;           // 0..31 within a 32-row issue
  const int sch   = t & 7;
#define WSTAGE(buf, c_, kh_) { \
    char* dst = Wsm[buf] + (w << 10); \
    _Pragma("unroll") \
    for (int i = 0; i < 4; ++i) { \
      const int row_ = i * 32 + srow0; \
      const unsigned short* src_ = Wb + (((size_t)(c_) * 128 + row_) << 7) + (kh_) * 64 + ((sch ^ (row_ & 7)) << 3); \
      gload16(src_, dst + i * 4096); \
    } }

  // W fragment read from LDS (swizzled)
#define WFRAG(buf, ksl, n_) \
    (*(const short8*)(Wsm[buf] + ((w * 32 + (n_) * 16 + ln) << 7) + ((((ksl) * 4 + q) ^ (ln & 7)) << 4)))

  f32x4 accH[2][2], accG[2][2];
  const int erow = t >> 3;            // 0..31
  const int colb = (t & 7) * 4;
  const size_t ebase0 = (size_t)(r0 + erow) * 2048 + colb;

  // prologue: stage c=0 both K-halves; prefetch epilogue c=0
  WSTAGE(0, 0, 0)
  WSTAGE(1, 0, 1)
  float4 exC[4], edC[4], exN[4], edN[4];
#pragma unroll
  for (int j = 0; j < 4; ++j) {
    exC[j] = *(const float4*)&x [ebase0 + j * 32];
    edC[j] = *(const float4*)&xd[ebase0 + j * 32];
  }
  __syncthreads();

  float rsum = 0.f, ssum = 0.f;
  for (int c = 0; c < 16; ++c) {
    // zero accumulators for this column tile
#pragma unroll
    for (int m = 0; m < 2; ++m)
#pragma unroll
      for (int n = 0; n < 2; ++n) {
        accH[m][n] = (f32x4){0.f, 0.f, 0.f, 0.f};
        accG[m][n] = (f32x4){0.f, 0.f, 0.f, 0.f};
      }
    // ---- compute K-half 0 (buf0) ----
#pragma unroll
    for (int ksl = 0; ksl < 2; ++ksl) {
      short8 bw0 = WFRAG(0, ksl, 0);
      short8 bw1 = WFRAG(0, ksl, 1);
      accH[0][0] = __builtin_amdgcn_mfma_f32_16x16x32_bf16(fh[0][ksl], bw0, accH[0][0], 0, 0, 0);
      accH[0][1] = __builtin_amdgcn_mfma_f32_16x16x32_bf16(fh[0][ksl], bw1, accH[0][1], 0, 0, 0);
      accH[1][0] = __builtin_amdgcn_mfma_f32_16x16x32_bf16(fh[1][ksl], bw0, accH[1][0], 0, 0, 0);
      accH[1][1] = __builtin_amdgcn_mfma_f32_16x16x32_bf16(fh[1][ksl], bw1, accH[1][1], 0, 0, 0);
      accG[0][0] = __builtin_amdgcn_mfma_f32_16x16x32_bf16(fg[0][ksl], bw0, accG[0][0], 0, 0, 0);
      accG[0][1] = __builtin_amdgcn_mfma_f32_16x16x32_bf16(fg[0][ksl], bw1, accG[0][1], 0, 0, 0);
      accG[1][0] = __builtin_amdgcn_mfma_f32_16x16x32_bf16(fg[1][ksl], bw0, accG[1][0], 0, 0, 0);
      accG[1][1] = __builtin_amdgcn_mfma_f32_16x16x32_bf16(fg[1][ksl], bw1, accG[1][1], 0, 0, 0);
    }
    __syncthreads();                       // all waves done with buf0
    if (c < 15) {
      WSTAGE(0, c + 1, 0)                  // restage buf0 for next tile
#pragma unroll
      for (int j = 0; j < 4; ++j) {        // prefetch next tile's x/xd
        exN[j] = *(const float4*)&x [ebase0 + (c + 1) * 128 + j * 32];
        edN[j] = *(const float4*)&xd[ebase0 + (c + 1) * 128 + j * 32];
      }
    }
    // ---- compute K-half 1 (buf1) ----
#pragma unroll
    for (int ksl = 0; ksl < 2; ++ksl) {
      short8 bw0 = WFRAG(1, ksl, 0);
      short8 bw1 = WFRAG(1, ksl, 1);
      accH[0][0] = __builtin_amdgcn_mfma_f32_16x16x32_bf16(fh[0][2 + ksl], bw0, accH[0][0], 0, 0, 0);
      accH[0][1] = __builtin_amdgcn_mfma_f32_16x16x32_bf16(fh[0][2 + ksl], bw1, accH[0][1], 0, 0, 0);
      accH[1][0] = __builtin_amdgcn_mfma_f32_16x16x32_bf16(fh[1][2 + ksl], bw0, accH[1][0], 0, 0, 0);
      accH[1][1] = __builtin_amdgcn_mfma_f32_16x16x32_bf16(fh[1][2 + ksl], bw1, accH[1][1], 0, 0, 0);
      accG[0][0] = __builtin_amdgcn_mfma_f32_16x16x32_bf16(fg[0][2 + ksl], bw0, accG[0][0], 0, 0, 0);
      accG[0][1] = __builtin_amdgcn_mfma_f32_16x16x32_bf16(fg[0][2 + ksl], bw1, accG[0][1], 0, 0, 0);
      accG[1][0] = __builtin_amdgcn_mfma_f32_16x16x32_bf16(fg[1][2 + ksl], bw0, accG[1][0], 0, 0, 0);
      accG[1][1] = __builtin_amdgcn_mfma_f32_16x16x32_bf16(fg[1][2 + ksl], bw1, accG[1][1], 0, 0, 0);
    }
    // transpose accumulators into LDS (2-way conflicts only, stride 132)
#pragma unroll
    for (int m = 0; m < 2; ++m)
#pragma unroll
      for (int n = 0; n < 2; ++n)
#pragma unroll
        for (int r = 0; r < 4; ++r) {
          const int rr = m * 16 + q * 4 + r;
          const int cc = w * 32 + n * 16 + ln;
          sH[rr * 132 + cc] = accH[m][n][r];
          sG[rr * 132 + cc] = accG[m][n][r];
        }
    __syncthreads();                       // sH/sG ready; buf1 free
    if (c < 15) WSTAGE(1, c + 1, 1)        // restage buf1 for next tile
    // ---- epilogue for tile c (row-major, fully coalesced) ----
    {
      const size_t gb = ebase0 + (size_t)c * 128;
#pragma unroll
      for (int j = 0; j < 4; ++j) {
        const int cc = colb + j * 32;
        float4 hv = *(const float4*)&sH[erow * 132 + cc];
        float4 gv = *(const float4*)&sG[erow * 132 + cc];
        float4 bv = *(const float4*)&bias[c * 128 + cc];
        f32x4 xh = {hv.x + bv.x, hv.y + bv.y, hv.z + bv.z, hv.w + bv.w};
        __builtin_nontemporal_store(xh, (f32x4*)&xhat[gb + j * 32]);
        float e;
        e = exC[j].x - xh[0]; rsum = fmaf(e, e, rsum);
        e = exC[j].y - xh[1]; rsum = fmaf(e, e, rsum);
        e = exC[j].z - xh[2]; rsum = fmaf(e, e, rsum);
        e = exC[j].w - xh[3]; rsum = fmaf(e, e, rsum);
        e = edC[j].x - gv.x; ssum = fmaf(e, e, ssum);
        e = edC[j].y - gv.y; ssum = fmaf(e, e, ssum);
        e = edC[j].z - gv.z; ssum = fmaf(e, e, ssum);
        e = edC[j].w - gv.w; ssum = fmaf(e, e, ssum);
      }
    }
#pragma unroll
    for (int j = 0; j < 4; ++j) { exC[j] = exN[j]; edC[j] = edN[j]; }
    __syncthreads();                       // sH/sG free; staging drained
  }
#undef WSTAGE
#undef WFRAG

#pragma unroll
  for (int off = 32; off > 0; off >>= 1) {
    rsum += __shfl_down(rsum, off);
    ssum += __shfl_down(ssum, off);
  }
  if (L == 0) { red[w * 2] = rsum; red[w * 2 + 1] = ssum; }
  __syncthreads();
  if (t == 0) {
    pr[blockIdx.x] = red[0] + red[2] + red[4] + red[6];
    ps[blockIdx.x] = red[1] + red[3] + red[5] + red[7];
  }
}

// ---------------------------------------------------------------------------
// K5: reduce all partials + write the 6 scalar outputs
// pr/ps now 512 entries each; pe* 1024 each.
// ---------------------------------------------------------------------------
__global__ __launch_bounds__(256) void finalize_kernel(
    const float* __restrict__ pr, const float* __restrict__ ps,
    const float* __restrict__ pe0, const float* __restrict__ pe1,
    const float* __restrict__ pe2, const float* __restrict__ coef,
    float* __restrict__ outp)
{
  __shared__ float sred[4][5];
  const int t = threadIdx.x, L = t & 63, w = t >> 6;
  float s[5] = {0.f, 0.f, 0.f, 0.f, 0.f};
  if (t < 128) {                           // pr/ps: 512 floats each
    float4 a = *(const float4*)&pr[t * 4];
    float4 b = *(const float4*)&ps[t * 4];
    s[0] += a.x + a.y + a.z + a.w;
    s[1] += b.x + b.y + b.z + b.w;
  }
  if (t < 256) {                           // pe*: 1024 floats each
    float4 a = *(const float4*)&pe0[t * 4];
    float4 b = *(const float4*)&pe1[t * 4];
    float4 c = *(const float4*)&pe2[t * 4];
    s[2] += a.x + a.y + a.z + a.w;
    s[3] += b.x + b.y + b.z + b.w;
    s[4] += c.x + c.y + c.z + c.w;
  }
#pragma unroll
  for (int off = 32; off > 0; off >>= 1)
#pragma unroll
    for (int k = 0; k < 5; ++k) s[k] += __shfl_down(s[k], off);
  if (L == 0)
#pragma unroll
    for (int k = 0; k < 5; ++k) sred[w][k] = s[k];
  __syncthreads();
  if (t == 0) {
    float r[5];
#pragma unroll
    for (int k = 0; k < 5; ++k)
      r[k] = sred[0][k] + sred[1][k] + sred[2][k] + sred[3][k];
    outp[0] = r[2] * (1.0f / 16384.0f);      // loss_po
    outp[1] = r[3] * (1.0f / 16384.0f);      // loss_tr
    outp[2] = r[0] * (1.0f / 33554432.0f);   // recon
    outp[3] = r[1] * (1.0f / 33554432.0f);   // sindy_x
    outp[4] = r[4] * (1.0f / 49152.0f);      // sindy_z
    float l1 = 0.f;
    for (int i = 0; i < 21; ++i) l1 += fabsf(coef[i]);
    outp[5] = l1 * (1.0f / 21.0f);
  }
}

extern "C" void kernel_launch(void* const* d_in, const int* in_sizes, int n_in,
                              void* d_out, int out_size, void* d_ws, size_t ws_size,
                              hipStream_t stream) {
  (void)in_sizes; (void)n_in; (void)out_size; (void)ws_size;
  const float* x    = (const float*)d_in[0];
  const float* xd   = (const float*)d_in[1];
  const float* tr   = (const float*)d_in[2];
  const float* sz   = (const float*)d_in[3];
  const float* eW1  = (const float*)d_in[4];
  const float* eb1  = (const float*)d_in[5];
  const float* eW2  = (const float*)d_in[6];
  const float* eb2  = (const float*)d_in[7];
  const float* eW3  = (const float*)d_in[8];
  const float* eb3  = (const float*)d_in[9];
  const float* eW4  = (const float*)d_in[10];
  const float* eb4  = (const float*)d_in[11];
  const float* dW1  = (const float*)d_in[12];
  const float* db1  = (const float*)d_in[13];
  const float* dW2  = (const float*)d_in[14];
  const float* db2  = (const float*)d_in[15];
  const float* dW3  = (const float*)d_in[16];
  const float* db3  = (const float*)d_in[17];
  const float* dW4  = (const float*)d_in[18];
  const float* db4  = (const float*)d_in[19];
  const float* coef = (const float*)d_in[20];

  float* ws = (float*)d_ws;
  float* a1   = ws;                                       // 2097152 f32
  float* dz1  = ws + 2097152;                             // 2097152 f32
  float* zdp  = ws + 4194304;                             // 49152 f32
  unsigned short* h3b = (unsigned short*)(ws + 4243472);  // 2097152 bf16
  unsigned short* g3b = (unsigned short*)(ws + 5292048);  // 2097152 bf16
  unsigned short* Wb1 = (unsigned short*)(ws + 6340624);  // 262144 bf16
  unsigned short* Wb4 = (unsigned short*)(ws + 6471696);  // 262144 bf16
  // partial-sum arrays alias the Wb1 region (dead after enc1_mfma)
  float* pr  = ws + 6340624;                              // 512 f32
  float* ps  = ws + 6348816;                              // 512 f32
  float* pe0 = ws + 6357008;                              // 1024 f32
  float* pe1 = ws + 6361104;                              // 1024 f32
  float* pe2 = ws + 6365200;                              // 1024 f32

  float* z_out = (float*)d_out;                           // 16384*3
  float* xhat  = (float*)d_out + 49152;                   // 16384*2048
  float* scal  = (float*)d_out + 49152 + 33554432;        // 6 scalars

  wcvt_kernel<<<1024, 256, 0, stream>>>(eW1, dW4, Wb1, Wb4);
  enc1_mfma<<<512, 256, 0, stream>>>(x, xd, tr, Wb1, eW1, eb1, a1, dz1);
  enc_small_kernel<<<1024, 256, 0, stream>>>(a1, dz1, eW2, eb2, eW3, eb3, eW4, eb4,
                                             coef, sz, tr, z_out, zdp, pe0, pe1, pe2);
  dec_small_kernel<<<1024, 256, 0, stream>>>(z_out, zdp, dW1, db1, dW2, db2, dW3, db3,
                                             h3b, g3b);
  dec4_mfma<<<512, 256, 0, stream>>>(h3b, g3b, Wb4, db4, x, xd, xhat, pr, ps);
  finalize_kernel<<<1, 256, 0, stream>>>(pr, ps, pe0, pe1, pe2, coef, scal);
}

// Round 7
// 484.277 us; speedup vs baseline: 1.2975x; 1.0571x over previous
//
#include <hip/hip_runtime.h>
#include <hip/hip_bf16.h>
#include <math.h>

typedef __attribute__((ext_vector_type(8))) short short8;
typedef __attribute__((ext_vector_type(4))) float f32x4;

__device__ __forceinline__ float sigm(float v) { return 1.0f / (1.0f + expf(-v)); }
__device__ __forceinline__ unsigned short f2b(float f) {
  __hip_bfloat16 h = __float2bfloat16(f);
  return __builtin_bit_cast(unsigned short, h);
}
__device__ __forceinline__ void gload16(const void* g, void* l) {
  __builtin_amdgcn_global_load_lds(
      (const __attribute__((address_space(1))) unsigned int*)g,
      (__attribute__((address_space(3))) unsigned int*)l, 16, 0, 0);
}
__device__ __forceinline__ short8 pack8(float4 a, float4 b) {
  short8 r;
  r[0] = (short)f2b(a.x); r[1] = (short)f2b(a.y);
  r[2] = (short)f2b(a.z); r[3] = (short)f2b(a.w);
  r[4] = (short)f2b(b.x); r[5] = (short)f2b(b.y);
  r[6] = (short)f2b(b.z); r[7] = (short)f2b(b.w);
  return r;
}

// ---------------------------------------------------------------------------
// K0: pre-convert eW1[:, :2048] -> Wb1 bf16 [128][2048], dW4 -> Wb4 bf16 [2048][128]
// ---------------------------------------------------------------------------
__global__ __launch_bounds__(256) void wcvt_kernel(
    const float* __restrict__ eW1, const float* __restrict__ dW4,
    unsigned short* __restrict__ Wb1, unsigned short* __restrict__ Wb4)
{
  int idx = blockIdx.x * 256 + threadIdx.x;   // 0..262143
  int o = idx >> 11, k = idx & 2047;
  Wb1[idx] = f2b(eW1[(size_t)o * 2049 + k]);
  Wb4[idx] = f2b(dW4[idx]);
}

// ---------------------------------------------------------------------------
// K1: MFMA dual GEMM: accx = x@W.T, accd = xd@W.T (bf16 mfma, fp32 acc)
// v6: counted-vmcnt pipeline (T3/T4). Raw s_barrier + s_waitcnt vmcnt(8):
// next tile's 8 global_load_lds stay in flight ACROSS the barrier; only the
// current buffer's 8 oldest are waited. No vmem drain at the second barrier.
// ---------------------------------------------------------------------------
__global__ __launch_bounds__(256) void enc1_mfma(
    const float* __restrict__ x, const float* __restrict__ xd,
    const float* __restrict__ tr, const unsigned short* __restrict__ Wb,
    const float* __restrict__ Wfull, const float* __restrict__ bias,
    float* __restrict__ a1, float* __restrict__ dz1)
{
  __shared__ __align__(16) char sm[65536];
  const int t = threadIdx.x;
  const int w = t >> 6, L = t & 63, q = L >> 4, ln = L & 15;
  const int r0 = blockIdx.x * 32;

  const int arow  = t >> 4;
  const int acolf = (((t & 15) ^ arow) & 15) << 2;
  const int wrow  = t >> 3;
  const int wcols = (((t & 7) ^ (wrow & 7)) & 7) << 3;
  const float* xsrc = x  + (size_t)(r0 + arow) * 2048 + acolf;
  const float* dsrc = xd + (size_t)(r0 + arow) * 2048 + acolf;
  const unsigned short* wsrc = Wb + (size_t)wrow * 2048 + wcols;
  const int wb = (t >> 6) << 10;

#define STAGE(c, kt) { \
    const int kb = (kt) * 64; \
    char* bA_ = sm + (c) * 32768; \
    gload16(xsrc + kb,          bA_ + wb); \
    gload16(xsrc + kb + 32768,  bA_ + wb + 4096); \
    gload16(dsrc + kb,          bA_ + 8192 + wb); \
    gload16(dsrc + kb + 32768,  bA_ + 8192 + wb + 4096); \
    gload16(wsrc + kb,          bA_ + 16384 + wb); \
    gload16(wsrc + kb + 65536,  bA_ + 16384 + wb + 4096); \
    gload16(wsrc + kb + 131072, bA_ + 16384 + wb + 8192); \
    gload16(wsrc + kb + 196608, bA_ + 16384 + wb + 12288); }

  f32x4 accx[2][2], accd[2][2];
#pragma unroll
  for (int m = 0; m < 2; ++m)
#pragma unroll
    for (int n = 0; n < 2; ++n) {
      accx[m][n] = (f32x4){0.f, 0.f, 0.f, 0.f};
      accd[m][n] = (f32x4){0.f, 0.f, 0.f, 0.f};
    }

  STAGE(0, 0)
  for (int kt = 0; kt < 32; ++kt) {
    // issue next tile's staging, then wait ONLY the current buffer's 8 loads
    if (kt + 1 < 32) {
      STAGE((kt + 1) & 1, kt + 1)
      asm volatile("s_waitcnt vmcnt(8)" ::: "memory");
    } else {
      asm volatile("s_waitcnt vmcnt(0)" ::: "memory");
    }
    __builtin_amdgcn_sched_barrier(0);
    __builtin_amdgcn_s_barrier();          // all waves' current-buffer writes visible
    __builtin_amdgcn_sched_barrier(0);

    const char* bA = sm + (kt & 1) * 32768;
    const char* bD = bA + 8192;
    const char* bW = bA + 16384;
#pragma unroll
    for (int ks = 0; ks < 2; ++ks) {
      short8 ax[2], ad[2], bw[2];
#pragma unroll
      for (int m = 0; m < 2; ++m) {
        const int rowb = (m * 16 + ln) * 256;
        const int off = ks * 128 + q * 32;
        float4 lo  = *(const float4*)(bA + rowb + ((off     ) ^ (ln << 4)));
        float4 hi  = *(const float4*)(bA + rowb + ((off + 16) ^ (ln << 4)));
        float4 dlo = *(const float4*)(bD + rowb + ((off     ) ^ (ln << 4)));
        float4 dhi = *(const float4*)(bD + rowb + ((off + 16) ^ (ln << 4)));
        ax[m] = pack8(lo, hi);
        ad[m] = pack8(dlo, dhi);
      }
#pragma unroll
      for (int n = 0; n < 2; ++n) {
        const int row = w * 32 + n * 16 + ln;
        const int off = ks * 64 + q * 16;
        bw[n] = *(const short8*)(bW + row * 128 + (off ^ ((ln & 7) << 4)));
      }
#pragma unroll
      for (int m = 0; m < 2; ++m)
#pragma unroll
        for (int n = 0; n < 2; ++n) {
          accx[m][n] = __builtin_amdgcn_mfma_f32_16x16x32_bf16(ax[m], bw[n], accx[m][n], 0, 0, 0);
          accd[m][n] = __builtin_amdgcn_mfma_f32_16x16x32_bf16(ad[m], bw[n], accd[m][n], 0, 0, 0);
        }
    }
    if (kt + 1 < 32) {
      // protect current buffer from next iteration's restage; NO vmem drain here
      asm volatile("s_waitcnt lgkmcnt(0)" ::: "memory");
      __builtin_amdgcn_sched_barrier(0);
      __builtin_amdgcn_s_barrier();
      __builtin_amdgcn_sched_barrier(0);
    }
  }
#undef STAGE

#pragma unroll
  for (int m = 0; m < 2; ++m) {
#pragma unroll
    for (int r = 0; r < 4; ++r) {
      const int row = r0 + m * 16 + q * 4 + r;
      const float trv = tr[row];
#pragma unroll
      for (int n = 0; n < 2; ++n) {
        const int col = w * 32 + n * 16 + ln;
        const float wl = Wfull[(size_t)col * 2049 + 2048];
        float p = accx[m][n][r] + trv * wl + bias[col];
        float g = accd[m][n][r] + trv * wl;
        float a = sigm(p);
        a1 [(size_t)row * 128 + col] = a;
        dz1[(size_t)row * 128 + col] = a * (1.f - a) * g;
      }
    }
  }
}

// ---------------------------------------------------------------------------
// K2: encoder layers 2-4 (unchanged).
// ---------------------------------------------------------------------------
__global__ __launch_bounds__(256) void enc_small_kernel(
    const float* __restrict__ a1, const float* __restrict__ dz1,
    const float* __restrict__ W2, const float* __restrict__ b2,
    const float* __restrict__ W3, const float* __restrict__ b3,
    const float* __restrict__ W4, const float* __restrict__ b4,
    const float* __restrict__ coef, const float* __restrict__ size_in,
    const float* __restrict__ treat,
    float* __restrict__ z_out, float* __restrict__ zdp_out,
    float* __restrict__ pe0, float* __restrict__ pe1, float* __restrict__ pe2)
{
  __shared__ float sW2[64 * 129];
  __shared__ float sW3[32 * 65];
  __shared__ float sW4[96];
  __shared__ float sB2[64], sB3[32], sB4[3], sC[21];
  __shared__ __align__(16) float a1s[16 * 128], d1s[16 * 128];
  __shared__ float a2s[16 * 64],  d2s[16 * 64];
  __shared__ float a3s[16 * 32],  d3s[16 * 32];
  __shared__ float zs[48], zds[48];
  __shared__ float rowl[16][3];
  const int t = threadIdx.x;
  for (int i = t; i < 64 * 128; i += 256) sW2[(i >> 7) * 129 + (i & 127)] = W2[i];
  for (int i = t; i < 32 * 64;  i += 256) sW3[(i >> 6) * 65  + (i & 63)]  = W3[i];
  if (t < 96) sW4[t] = W4[t];
  if (t < 64) sB2[t] = b2[t];
  if (t < 32) sB3[t] = b3[t];
  if (t < 3)  sB4[t] = b4[t];
  if (t < 21) sC[t]  = coef[t];
  const int r0 = blockIdx.x * 16;
  {
    const float4* a1g = (const float4*)(a1  + (size_t)r0 * 128);
    const float4* d1g = (const float4*)(dz1 + (size_t)r0 * 128);
    float4* a1s4 = (float4*)a1s;
    float4* d1s4 = (float4*)d1s;
#pragma unroll
    for (int i = 0; i < 2; ++i) {
      a1s4[t + i * 256] = a1g[t + i * 256];
      d1s4[t + i * 256] = d1g[t + i * 256];
    }
  }
  __syncthreads();
  {
    const int o = t & 63, rb = t >> 6;
    float p[4] = {0.f, 0.f, 0.f, 0.f}, g[4] = {0.f, 0.f, 0.f, 0.f};
#pragma unroll 4
    for (int k = 0; k < 128; ++k) {
      const float wv = sW2[o * 129 + k];
#pragma unroll
      for (int u = 0; u < 4; ++u) {
        p[u] = fmaf(wv, a1s[(rb + u * 4) * 128 + k], p[u]);
        g[u] = fmaf(wv, d1s[(rb + u * 4) * 128 + k], g[u]);
      }
    }
#pragma unroll
    for (int u = 0; u < 4; ++u) {
      float a = sigm(p[u] + sB2[o]);
      a2s[(rb + u * 4) * 64 + o] = a;
      d2s[(rb + u * 4) * 64 + o] = a * (1.f - a) * g[u];
    }
  }
  __syncthreads();
  {
    const int o = t & 31, r3 = t >> 5;
    float p[2] = {0.f, 0.f}, g[2] = {0.f, 0.f};
#pragma unroll 4
    for (int k = 0; k < 64; ++k) {
      const float wv = sW3[o * 65 + k];
#pragma unroll
      for (int u = 0; u < 2; ++u) {
        p[u] = fmaf(wv, a2s[(r3 + u * 8) * 64 + k], p[u]);
        g[u] = fmaf(wv, d2s[(r3 + u * 8) * 64 + k], g[u]);
      }
    }
#pragma unroll
    for (int u = 0; u < 2; ++u) {
      float a = sigm(p[u] + sB3[o]);
      a3s[(r3 + u * 8) * 32 + o] = a;
      d3s[(r3 + u * 8) * 32 + o] = a * (1.f - a) * g[u];
    }
  }
  __syncthreads();
  if (t < 48) {
    const int r = t / 3, j = t % 3;
    float p = 0.f, g = 0.f;
#pragma unroll
    for (int k = 0; k < 32; ++k) {
      float wv = sW4[j * 32 + k];
      p = fmaf(wv, a3s[r * 32 + k], p);
      g = fmaf(wv, d3s[r * 32 + k], g);
    }
    float zv = p + sB4[j];
    zs [r * 3 + j] = zv;
    zds[r * 3 + j] = g;
    z_out[(size_t)(r0 + r) * 3 + j] = zv;
  }
  __syncthreads();
  if (t < 16) {
    const int r = t;
    float s = zs[r * 3 + 0], d = zs[r * 3 + 1], tt = zs[r * 3 + 2];
    float th[7] = {1.f, s, s * s, s * d, s * tt, s * s * d, s * s * tt};
    float sz = 0.f;
    for (int j = 0; j < 3; ++j) {
      float zp = 0.f;
#pragma unroll
      for (int i = 0; i < 7; ++i) zp = fmaf(th[i], sC[i * 3 + j], zp);
      zdp_out[(size_t)(r0 + r) * 3 + j] = zp;
      float e = zds[r * 3 + j] - zp;
      sz += e * e;
    }
    float e0 = s - size_in[r0 + r];
    float logit = tt;
    float trv = treat[r0 + r];
    float lt = fmaxf(logit, 0.f) + log1pf(expf(-fabsf(logit))) - logit * trv;
    rowl[r][0] = e0 * e0; rowl[r][1] = lt; rowl[r][2] = sz;
  }
  __syncthreads();
  if (t == 0) {
    float s0 = 0, s1 = 0, s2 = 0;
    for (int r = 0; r < 16; ++r) { s0 += rowl[r][0]; s1 += rowl[r][1]; s2 += rowl[r][2]; }
    pe0[blockIdx.x] = s0;
    pe1[blockIdx.x] = s1;
    pe2[blockIdx.x] = s2;
  }
}

// ---------------------------------------------------------------------------
// K3: decoder layers 1-3 (unchanged).
// ---------------------------------------------------------------------------
__global__ __launch_bounds__(256) void dec_small_kernel(
    const float* __restrict__ z_in, const float* __restrict__ zdp,
    const float* __restrict__ W1, const float* __restrict__ b1,
    const float* __restrict__ W2, const float* __restrict__ b2,
    const float* __restrict__ W3, const float* __restrict__ b3,
    unsigned short* __restrict__ h3b, unsigned short* __restrict__ g3b)
{
  __shared__ float sW1[96], sB1[32];
  __shared__ float sW2[64 * 33], sB2[64];
  __shared__ float sW3[128 * 65], sB3[128];
  __shared__ float zr[48], zp[48];
  __shared__ float h1s[16 * 32], g1s[16 * 32];
  __shared__ float h2s[16 * 64], g2s[16 * 64];
  const int t = threadIdx.x;
  for (int i = t; i < 64 * 32;  i += 256) sW2[(i >> 5) * 33 + (i & 31)] = W2[i];
  for (int i = t; i < 128 * 64; i += 256) sW3[(i >> 6) * 65 + (i & 63)] = W3[i];
  if (t < 96)  sW1[t] = W1[t];
  if (t < 32)  sB1[t] = b1[t];
  if (t < 64)  sB2[t] = b2[t];
  if (t < 128) sB3[t] = b3[t];
  const int r0 = blockIdx.x * 16;
  if (t < 48) { zr[t] = z_in[(size_t)r0 * 3 + t]; zp[t] = zdp[(size_t)r0 * 3 + t]; }
  __syncthreads();
  {
    const int o = t & 31, rb = t >> 5;
    float p[2], g[2];
#pragma unroll
    for (int u = 0; u < 2; ++u) {
      const int r = rb + u * 8;
      float pp = sB1[o], gg = 0.f;
#pragma unroll
      for (int k = 0; k < 3; ++k) {
        float wv = sW1[o * 3 + k];
        pp = fmaf(wv, zr[r * 3 + k], pp);
        gg = fmaf(wv, zp[r * 3 + k], gg);
      }
      p[u] = pp; g[u] = gg;
    }
#pragma unroll
    for (int u = 0; u < 2; ++u) {
      const int r = rb + u * 8;
      float h = sigm(p[u]);
      h1s[r * 32 + o] = h; g1s[r * 32 + o] = h * (1.f - h) * g[u];
    }
  }
  __syncthreads();
  {
    const int o = t & 63, rb = t >> 6;
    float p[4], g[4];
#pragma unroll
    for (int u = 0; u < 4; ++u) { p[u] = sB2[o]; g[u] = 0.f; }
#pragma unroll 4
    for (int k = 0; k < 32; ++k) {
      const float wv = sW2[o * 33 + k];
#pragma unroll
      for (int u = 0; u < 4; ++u) {
        p[u] = fmaf(wv, h1s[(rb + u * 4) * 32 + k], p[u]);
        g[u] = fmaf(wv, g1s[(rb + u * 4) * 32 + k], g[u]);
      }
    }
#pragma unroll
    for (int u = 0; u < 4; ++u) {
      float h = sigm(p[u]);
      h2s[(rb + u * 4) * 64 + o] = h;
      g2s[(rb + u * 4) * 64 + o] = h * (1.f - h) * g[u];
    }
  }
  __syncthreads();
  {
    const int o = t & 127, rb2 = t >> 7;
    float p[8], g[8];
#pragma unroll
    for (int u = 0; u < 8; ++u) { p[u] = sB3[o]; g[u] = 0.f; }
#pragma unroll 4
    for (int k = 0; k < 64; ++k) {
      const float wv = sW3[o * 65 + k];
#pragma unroll
      for (int u = 0; u < 8; ++u) {
        p[u] = fmaf(wv, h2s[(rb2 + u * 2) * 64 + k], p[u]);
        g[u] = fmaf(wv, g2s[(rb2 + u * 2) * 64 + k], g[u]);
      }
    }
#pragma unroll
    for (int u = 0; u < 8; ++u) {
      const int r = rb2 + u * 2;
      float h = sigm(p[u]);
      h3b[(size_t)(r0 + r) * 128 + o] = f2b(h);
      g3b[(size_t)(r0 + r) * 128 + o] = f2b(h * (1.f - h) * g[u]);
    }
  }
}

// ---------------------------------------------------------------------------
// K4: dec4 (unchanged from r6). 512 row-blocks, 16 column tiles, H/G in regs,
// W staged via global_load_lds dbuf, epilogue prefetch one tile ahead.
// ---------------------------------------------------------------------------
__global__ __launch_bounds__(256, 2) void dec4_mfma(
    const unsigned short* __restrict__ h3b, const unsigned short* __restrict__ g3b,
    const unsigned short* __restrict__ Wb, const float* __restrict__ bias,
    const float* __restrict__ x, const float* __restrict__ xd,
    float* __restrict__ xhat, float* __restrict__ pr, float* __restrict__ ps)
{
  __shared__ __align__(16) char Wsm[2][16384];   // K-half W tiles (dbuf)
  __shared__ float sH[32 * 132];
  __shared__ float sG[32 * 132];
  __shared__ float red[8];
  const int t = threadIdx.x, w = t >> 6, L = t & 63, q = L >> 4, ln = L & 15;
  const int r0 = blockIdx.x * 32;

  short8 fh[2][4], fg[2][4];
  {
    const size_t a0 = (size_t)(r0 + ln) * 128;
    const size_t a1 = (size_t)(r0 + 16 + ln) * 128;
#pragma unroll
    for (int ks = 0; ks < 4; ++ks) {
      const int kb = ks * 32 + q * 8;
      fh[0][ks] = *(const short8*)&h3b[a0 + kb];
      fh[1][ks] = *(const short8*)&h3b[a1 + kb];
      fg[0][ks] = *(const short8*)&g3b[a0 + kb];
      fg[1][ks] = *(const short8*)&g3b[a1 + kb];
    }
  }

  const int srow0 = t >> 3;
  const int sch   = t & 7;
#define WSTAGE(buf, c_, kh_) { \
    char* dst = Wsm[buf] + (w << 10); \
    _Pragma("unroll") \
    for (int i = 0; i < 4; ++i) { \
      const int row_ = i * 32 + srow0; \
      const unsigned short* src_ = Wb + (((size_t)(c_) * 128 + row_) << 7) + (kh_) * 64 + ((sch ^ (row_ & 7)) << 3); \
      gload16(src_, dst + i * 4096); \
    } }

#define WFRAG(buf, ksl, n_) \
    (*(const short8*)(Wsm[buf] + ((w * 32 + (n_) * 16 + ln) << 7) + ((((ksl) * 4 + q) ^ (ln & 7)) << 4)))

  f32x4 accH[2][2], accG[2][2];
  const int erow = t >> 3;
  const int colb = (t & 7) * 4;
  const size_t ebase0 = (size_t)(r0 + erow) * 2048 + colb;

  WSTAGE(0, 0, 0)
  WSTAGE(1, 0, 1)
  float4 exC[4], edC[4], exN[4], edN[4];
#pragma unroll
  for (int j = 0; j < 4; ++j) {
    exC[j] = *(const float4*)&x [ebase0 + j * 32];
    edC[j] = *(const float4*)&xd[ebase0 + j * 32];
  }
  __syncthreads();

  float rsum = 0.f, ssum = 0.f;
  for (int c = 0; c < 16; ++c) {
#pragma unroll
    for (int m = 0; m < 2; ++m)
#pragma unroll
      for (int n = 0; n < 2; ++n) {
        accH[m][n] = (f32x4){0.f, 0.f, 0.f, 0.f};
        accG[m][n] = (f32x4){0.f, 0.f, 0.f, 0.f};
      }
#pragma unroll
    for (int ksl = 0; ksl < 2; ++ksl) {
      short8 bw0 = WFRAG(0, ksl, 0);
      short8 bw1 = WFRAG(0, ksl, 1);
      accH[0][0] = __builtin_amdgcn_mfma_f32_16x16x32_bf16(fh[0][ksl], bw0, accH[0][0], 0, 0, 0);
      accH[0][1] = __builtin_amdgcn_mfma_f32_16x16x32_bf16(fh[0][ksl], bw1, accH[0][1], 0, 0, 0);
      accH[1][0] = __builtin_amdgcn_mfma_f32_16x16x32_bf16(fh[1][ksl], bw0, accH[1][0], 0, 0, 0);
      accH[1][1] = __builtin_amdgcn_mfma_f32_16x16x32_bf16(fh[1][ksl], bw1, accH[1][1], 0, 0, 0);
      accG[0][0] = __builtin_amdgcn_mfma_f32_16x16x32_bf16(fg[0][ksl], bw0, accG[0][0], 0, 0, 0);
      accG[0][1] = __builtin_amdgcn_mfma_f32_16x16x32_bf16(fg[0][ksl], bw1, accG[0][1], 0, 0, 0);
      accG[1][0] = __builtin_amdgcn_mfma_f32_16x16x32_bf16(fg[1][ksl], bw0, accG[1][0], 0, 0, 0);
      accG[1][1] = __builtin_amdgcn_mfma_f32_16x16x32_bf16(fg[1][ksl], bw1, accG[1][1], 0, 0, 0);
    }
    __syncthreads();
    if (c < 15) {
      WSTAGE(0, c + 1, 0)
#pragma unroll
      for (int j = 0; j < 4; ++j) {
        exN[j] = *(const float4*)&x [ebase0 + (c + 1) * 128 + j * 32];
        edN[j] = *(const float4*)&xd[ebase0 + (c + 1) * 128 + j * 32];
      }
    }
#pragma unroll
    for (int ksl = 0; ksl < 2; ++ksl) {
      short8 bw0 = WFRAG(1, ksl, 0);
      short8 bw1 = WFRAG(1, ksl, 1);
      accH[0][0] = __builtin_amdgcn_mfma_f32_16x16x32_bf16(fh[0][2 + ksl], bw0, accH[0][0], 0, 0, 0);
      accH[0][1] = __builtin_amdgcn_mfma_f32_16x16x32_bf16(fh[0][2 + ksl], bw1, accH[0][1], 0, 0, 0);
      accH[1][0] = __builtin_amdgcn_mfma_f32_16x16x32_bf16(fh[1][2 + ksl], bw0, accH[1][0], 0, 0, 0);
      accH[1][1] = __builtin_amdgcn_mfma_f32_16x16x32_bf16(fh[1][2 + ksl], bw1, accH[1][1], 0, 0, 0);
      accG[0][0] = __builtin_amdgcn_mfma_f32_16x16x32_bf16(fg[0][2 + ksl], bw0, accG[0][0], 0, 0, 0);
      accG[0][1] = __builtin_amdgcn_mfma_f32_16x16x32_bf16(fg[0][2 + ksl], bw1, accG[0][1], 0, 0, 0);
      accG[1][0] = __builtin_amdgcn_mfma_f32_16x16x32_bf16(fg[1][2 + ksl], bw0, accG[1][0], 0, 0, 0);
      accG[1][1] = __builtin_amdgcn_mfma_f32_16x16x32_bf16(fg[1][2 + ksl], bw1, accG[1][1], 0, 0, 0);
    }
#pragma unroll
    for (int m = 0; m < 2; ++m)
#pragma unroll
      for (int n = 0; n < 2; ++n)
#pragma unroll
        for (int r = 0; r < 4; ++r) {
          const int rr = m * 16 + q * 4 + r;
          const int cc = w * 32 + n * 16 + ln;
          sH[rr * 132 + cc] = accH[m][n][r];
          sG[rr * 132 + cc] = accG[m][n][r];
        }
    __syncthreads();
    if (c < 15) WSTAGE(1, c + 1, 1)
    {
      const size_t gb = ebase0 + (size_t)c * 128;
#pragma unroll
      for (int j = 0; j < 4; ++j) {
        const int cc = colb + j * 32;
        float4 hv = *(const float4*)&sH[erow * 132 + cc];
        float4 gv = *(const float4*)&sG[erow * 132 + cc];
        float4 bv = *(const float4*)&bias[c * 128 + cc];
        f32x4 xh = {hv.x + bv.x, hv.y + bv.y, hv.z + bv.z, hv.w + bv.w};
        __builtin_nontemporal_store(xh, (f32x4*)&xhat[gb + j * 32]);
        float e;
        e = exC[j].x - xh[0]; rsum = fmaf(e, e, rsum);
        e = exC[j].y - xh[1]; rsum = fmaf(e, e, rsum);
        e = exC[j].z - xh[2]; rsum = fmaf(e, e, rsum);
        e = exC[j].w - xh[3]; rsum = fmaf(e, e, rsum);
        e = edC[j].x - gv.x; ssum = fmaf(e, e, ssum);
        e = edC[j].y - gv.y; ssum = fmaf(e, e, ssum);
        e = edC[j].z - gv.z; ssum = fmaf(e, e, ssum);
        e = edC[j].w - gv.w; ssum = fmaf(e, e, ssum);
      }
    }
#pragma unroll
    for (int j = 0; j < 4; ++j) { exC[j] = exN[j]; edC[j] = edN[j]; }
    __syncthreads();
  }
#undef WSTAGE
#undef WFRAG

#pragma unroll
  for (int off = 32; off > 0; off >>= 1) {
    rsum += __shfl_down(rsum, off);
    ssum += __shfl_down(ssum, off);
  }
  if (L == 0) { red[w * 2] = rsum; red[w * 2 + 1] = ssum; }
  __syncthreads();
  if (t == 0) {
    pr[blockIdx.x] = red[0] + red[2] + red[4] + red[6];
    ps[blockIdx.x] = red[1] + red[3] + red[5] + red[7];
  }
}

// ---------------------------------------------------------------------------
// K5: reduce all partials + write the 6 scalar outputs (unchanged).
// ---------------------------------------------------------------------------
__global__ __launch_bounds__(256) void finalize_kernel(
    const float* __restrict__ pr, const float* __restrict__ ps,
    const float* __restrict__ pe0, const float* __restrict__ pe1,
    const float* __restrict__ pe2, const float* __restrict__ coef,
    float* __restrict__ outp)
{
  __shared__ float sred[4][5];
  const int t = threadIdx.x, L = t & 63, w = t >> 6;
  float s[5] = {0.f, 0.f, 0.f, 0.f, 0.f};
  if (t < 128) {                           // pr/ps: 512 floats each
    float4 a = *(const float4*)&pr[t * 4];
    float4 b = *(const float4*)&ps[t * 4];
    s[0] += a.x + a.y + a.z + a.w;
    s[1] += b.x + b.y + b.z + b.w;
  }
  if (t < 256) {                           // pe*: 1024 floats each
    float4 a = *(const float4*)&pe0[t * 4];
    float4 b = *(const float4*)&pe1[t * 4];
    float4 c = *(const float4*)&pe2[t * 4];
    s[2] += a.x + a.y + a.z + a.w;
    s[3] += b.x + b.y + b.z + b.w;
    s[4] += c.x + c.y + c.z + c.w;
  }
#pragma unroll
  for (int off = 32; off > 0; off >>= 1)
#pragma unroll
    for (int k = 0; k < 5; ++k) s[k] += __shfl_down(s[k], off);
  if (L == 0)
#pragma unroll
    for (int k = 0; k < 5; ++k) sred[w][k] = s[k];
  __syncthreads();
  if (t == 0) {
    float r[5];
#pragma unroll
    for (int k = 0; k < 5; ++k)
      r[k] = sred[0][k] + sred[1][k] + sred[2][k] + sred[3][k];
    outp[0] = r[2] * (1.0f / 16384.0f);      // loss_po
    outp[1] = r[3] * (1.0f / 16384.0f);      // loss_tr
    outp[2] = r[0] * (1.0f / 33554432.0f);   // recon
    outp[3] = r[1] * (1.0f / 33554432.0f);   // sindy_x
    outp[4] = r[4] * (1.0f / 49152.0f);      // sindy_z
    float l1 = 0.f;
    for (int i = 0; i < 21; ++i) l1 += fabsf(coef[i]);
    outp[5] = l1 * (1.0f / 21.0f);
  }
}

extern "C" void kernel_launch(void* const* d_in, const int* in_sizes, int n_in,
                              void* d_out, int out_size, void* d_ws, size_t ws_size,
                              hipStream_t stream) {
  (void)in_sizes; (void)n_in; (void)out_size; (void)ws_size;
  const float* x    = (const float*)d_in[0];
  const float* xd   = (const float*)d_in[1];
  const float* tr   = (const float*)d_in[2];
  const float* sz   = (const float*)d_in[3];
  const float* eW1  = (const float*)d_in[4];
  const float* eb1  = (const float*)d_in[5];
  const float* eW2  = (const float*)d_in[6];
  const float* eb2  = (const float*)d_in[7];
  const float* eW3  = (const float*)d_in[8];
  const float* eb3  = (const float*)d_in[9];
  const float* eW4  = (const float*)d_in[10];
  const float* eb4  = (const float*)d_in[11];
  const float* dW1  = (const float*)d_in[12];
  const float* db1  = (const float*)d_in[13];
  const float* dW2  = (const float*)d_in[14];
  const float* db2  = (const float*)d_in[15];
  const float* dW3  = (const float*)d_in[16];
  const float* db3  = (const float*)d_in[17];
  const float* dW4  = (const float*)d_in[18];
  const float* db4  = (const float*)d_in[19];
  const float* coef = (const float*)d_in[20];

  float* ws = (float*)d_ws;
  float* a1   = ws;                                       // 2097152 f32
  float* dz1  = ws + 2097152;                             // 2097152 f32
  float* zdp  = ws + 4194304;                             // 49152 f32
  unsigned short* h3b = (unsigned short*)(ws + 4243472);  // 2097152 bf16
  unsigned short* g3b = (unsigned short*)(ws + 5292048);  // 2097152 bf16
  unsigned short* Wb1 = (unsigned short*)(ws + 6340624);  // 262144 bf16
  unsigned short* Wb4 = (unsigned short*)(ws + 6471696);  // 262144 bf16
  // partial-sum arrays alias the Wb1 region (dead after enc1_mfma)
  float* pr  = ws + 6340624;                              // 512 f32
  float* ps  = ws + 6348816;                              // 512 f32
  float* pe0 = ws + 6357008;                              // 1024 f32
  float* pe1 = ws + 6361104;                              // 1024 f32
  float* pe2 = ws + 6365200;                              // 1024 f32

  float* z_out = (float*)d_out;                           // 16384*3
  float* xhat  = (float*)d_out + 49152;                   // 16384*2048
  float* scal  = (float*)d_out + 49152 + 33554432;        // 6 scalars

  wcvt_kernel<<<1024, 256, 0, stream>>>(eW1, dW4, Wb1, Wb4);
  enc1_mfma<<<512, 256, 0, stream>>>(x, xd, tr, Wb1, eW1, eb1, a1, dz1);
  enc_small_kernel<<<1024, 256, 0, stream>>>(a1, dz1, eW2, eb2, eW3, eb3, eW4, eb4,
                                             coef, sz, tr, z_out, zdp, pe0, pe1, pe2);
  dec_small_kernel<<<1024, 256, 0, stream>>>(z_out, zdp, dW1, db1, dW2, db2, dW3, db3,
                                             h3b, g3b);
  dec4_mfma<<<512, 256, 0, stream>>>(h3b, g3b, Wb4, db4, x, xd, xhat, pr, ps);
  finalize_kernel<<<1, 256, 0, stream>>>(pr, ps, pe0, pe1, pe2, coef, scal);
}